// Round 4
// baseline (142.069 us; speedup 1.0000x reference)
//
#include <hip/hip_runtime.h>
#include <math.h>

// GraspCVAE loss, MI355X — round 12.
// R11 post-mortem: acc-line padding gave -4.8us (mega2 atomics ~5us, not 40).
// mega1 was INVARIANT at 42us across R9 (VALU -20%), R10 (2x blocks +
// prefetch) -> the shared saturated resource is the per-CU LDS pipe:
// ~1.1M ds_read_b128 broadcasts x ~12cyc = 50-63K cyc/CU vs 100K wall.
// R12 cuts ds_read COUNT via per-lane amortization:
//   * obj kernel: P_OBJ 12 (one tile, 256 blocks x 256thr) -> reads /3,
//     108 VALU per read-pair; single wave/SIMD self-hides latency via ILP.
//   * hand kernel: 128thr x m=6 (wave count halved) -> reads /2.
//   * mega2 unchanged (JS=8/HC=24 layout, padded accs).
// Profile note: harness ws-poison fills (~43us) crowd the top-5; total
// dur_us is the only readable signal now.

#define NB 32
#define NH 778
#define NO 3000
#define NZ 64
#define NP 204

#define JS8 8
#define JC8 98                        // ceil(778/8)
#define PO 12                         // obj pts per thread (12*256=3072>=3000)
#define HC24 24
#define HCS24 125                     // 3000/24
#define PH 6                          // hand pts per thread (6*128=768)

#define T2 12                         // mega2 obj tiles (256 pts)
#define FIN_OBJ_BLKS (NB * T2)                // 384
#define FIN_TAIL_BLKS ((NB * NH + 255) / 256) // 98
#define FIN_BLKS (FIN_OBJ_BLKS + FIN_TAIL_BLKS) // 482

#define NKEY (NB * NO)                // 96000
#define NHT  (NB * NH)                // 24896

// accumulator padding: each logical slot q lives at accs[q*ACC_STRIDE]
#define ACC_STRIDE 32                 // 32 floats = 128 B = own cache line
#define ACC_FLOATS 512                // 16 slots * 32

typedef unsigned int uint32;

// original order (used by PATH C)
__device__ __constant__ int c_prior[NP] = {
  697,698,699,700,712,713,714,715,737,738,739,740,741,743,744,745,746,748,749,750,
  753,754,755,756,757,758,759,760,761,762,763,764,765,766,767,768,
  46,47,48,49,164,165,166,167,194,195,223,237,238,280,281,298,301,317,320,323,
  324,325,326,327,328,329,330,331,332,333,340,341,342,343,344,345,346,347,348,349,
  350,351,352,353,354,355,
  356,357,358,359,375,376,386,387,396,397,402,403,413,429,433,434,435,436,437,438,
  439,440,441,442,443,444,452,453,454,455,456,459,460,461,462,463,464,465,466,467,
  468,469,470,471,484,485,486,496,497,506,507,513,514,524,545,546,547,548,549,550,
  551,552,553,555,563,564,565,566,567,570,572,573,574,575,576,577,578,
  580,581,582,583,600,601,602,614,615,624,625,630,631,641,663,664,665,666,667,668,
  670,672,680,681,682,683,684,686,687,688,689,690,691,692,693,694,695,
  73,96,98,99,772,774,775,777
};

// globally ascending sorted prior list (usable for ANY contiguous j-split)
__device__ __constant__ int c_prior_sorted[NP] = {
  46,47,48,49,73,96,98,99,164,165,166,167,194,
  195,223,237,238,280,281,298,301,317,320,323,324,325,326,327,328,329,330,331,
  332,333,340,341,342,343,344,345,346,347,348,349,350,351,352,353,354,355,356,
  357,358,359,375,376,386,387,
  396,397,402,403,413,429,433,434,435,436,437,438,439,440,441,442,443,444,452,
  453,454,455,456,459,460,461,462,463,464,465,466,467,468,469,470,471,484,485,
  486,496,497,506,507,513,514,524,545,546,547,548,549,550,551,552,553,555,563,
  564,565,566,567,570,572,573,574,575,576,577,578,580,581,582,583,
  600,601,602,614,615,624,625,630,631,641,663,664,665,666,667,668,670,672,680,
  681,682,683,684,686,687,688,689,690,691,692,693,694,695,697,698,699,700,712,
  713,714,715,737,738,739,740,741,743,744,745,746,748,749,750,753,754,755,756,
  757,758,759,760,761,762,763,764,765,766,767,768,772,774,775,777
};
// position ranges in c_prior_sorted for j in [s*98, (s+1)*98)
__device__ __constant__ int c_psplit8[9] = {0, 6, 14, 19, 58, 97, 131, 154, 204};

__device__ inline float wave_sum(float v) {
  v += __shfl_down(v, 32);
  v += __shfl_down(v, 16);
  v += __shfl_down(v, 8);
  v += __shfl_down(v, 4);
  v += __shfl_down(v, 2);
  v += __shfl_down(v, 1);
  return v;
}

// forced 3-operand VALU ops (R9: verified correct)
__device__ __forceinline__ float f_min3(float a, float b, float c) {
  float r;
  asm("v_min3_f32 %0, %1, %2, %3" : "=v"(r) : "v"(a), "v"(b), "v"(c));
  return r;
}
__device__ __forceinline__ float f_packao(float t, int j, uint32 mask) {
  float r;
  asm("v_and_or_b32 %0, %1, %2, %3" : "=v"(r) : "v"(t), "s"(mask), "v"(j));
  return r;
}

// ======================= dispatch 1a: obj -> hand NN =======================
// 256 blocks (32 b x 8 splits), 256 thr, 12 obj pts/thread (one tile).
__global__ __launch_bounds__(256) void obj_nn(
    const float* __restrict__ recon, const float* __restrict__ gt,
    const float* __restrict__ obj,
    float* __restrict__ keyR, float* __restrict__ keyG,
    float* __restrict__ priorK, float* __restrict__ accs)
{
  __shared__ float4 shA[JC8];   // recon split
  __shared__ float4 shB[JC8];   // gt split
  const int bid = blockIdx.x;
  const int tid = threadIdx.x;
  const uint32 KMASK = 0xFFFFFC00u;

  if (bid == 0) {  // zero padded accumulator region
    accs[tid] = 0.0f;
    accs[tid + 256] = 0.0f;
  }

  const int b     = bid >> 3;
  const int split = bid & 7;
  const int jbase = split * JC8;
  const int jcnt  = (NH - jbase < JC8) ? (NH - jbase) : JC8;  // 98 or 92

  for (int i = tid; i < jcnt; i += 256) {
    const float* p = recon + ((size_t)b * NH + jbase + i) * 3;
    float x = p[0], y = p[1], z = p[2];
    shA[i] = make_float4(x, y, z, x*x + y*y + z*z);
    const float* q = gt + ((size_t)b * NH + jbase + i) * 3;
    float gx = q[0], gy = q[1], gz = q[2];
    shB[i] = make_float4(gx, gy, gz, gx*gx + gy*gy + gz*gz);
  }
  __syncthreads();

  float nx[PO], ny[PO], nz[PO];
  bool val[PO];
  #pragma unroll
  for (int m = 0; m < PO; ++m) {
    const int o = m * 256 + tid;
    val[m] = (o < NO);
    float x = 0.f, y = 0.f, z = 0.f;
    if (val[m]) {
      const float* op = obj + ((size_t)b * NO + o) * 3;
      x = op[0]; y = op[1]; z = op[2];
    }
    nx[m] = -2.f * x; ny[m] = -2.f * y; nz[m] = -2.f * z;
  }

  float bR[PO], bG[PO], bP[PO];
  #pragma unroll
  for (int m = 0; m < PO; ++m) { bR[m] = 3.4e38f; bG[m] = 3.4e38f; bP[m] = 3.4e38f; }

  int i = 0;
  for (; i + 1 < jcnt; i += 2) {
    const int j0 = jbase + i, j1 = jbase + i + 1;
    float4 h0 = shA[i], h1 = shA[i + 1];
    float4 g0 = shB[i], g1 = shB[i + 1];
    #pragma unroll
    for (int m = 0; m < PO; ++m) {
      float t0 = fmaf(nx[m], h0.x, h0.w); t0 = fmaf(ny[m], h0.y, t0); t0 = fmaf(nz[m], h0.z, t0);
      float t1 = fmaf(nx[m], h1.x, h1.w); t1 = fmaf(ny[m], h1.y, t1); t1 = fmaf(nz[m], h1.z, t1);
      bR[m] = f_min3(bR[m], f_packao(t0, j0, KMASK), f_packao(t1, j1, KMASK));
      float u0 = fmaf(nx[m], g0.x, g0.w); u0 = fmaf(ny[m], g0.y, u0); u0 = fmaf(nz[m], g0.z, u0);
      float u1 = fmaf(nx[m], g1.x, g1.w); u1 = fmaf(ny[m], g1.y, u1); u1 = fmaf(nz[m], g1.z, u1);
      bG[m] = f_min3(bG[m], f_packao(u0, j0, KMASK), f_packao(u1, j1, KMASK));
    }
  }
  if (i < jcnt) {
    const int j0 = jbase + i;
    float4 h0 = shA[i], g0 = shB[i];
    #pragma unroll
    for (int m = 0; m < PO; ++m) {
      float t0 = fmaf(nx[m], h0.x, h0.w); t0 = fmaf(ny[m], h0.y, t0); t0 = fmaf(nz[m], h0.z, t0);
      bR[m] = fminf(bR[m], f_packao(t0, j0, KMASK));
      float u0 = fmaf(nx[m], g0.x, g0.w); u0 = fmaf(ny[m], g0.y, u0); u0 = fmaf(nz[m], g0.z, u0);
      bG[m] = fminf(bG[m], f_packao(u0, j0, KMASK));
    }
  }

  // partial prior-NN over this split's prior members (candidates in shA)
  const int pk0 = c_psplit8[split], pk1 = c_psplit8[split + 1];
  int k = pk0;
  for (; k + 1 < pk1; k += 2) {
    float4 ha = shA[c_prior_sorted[k] - jbase];
    float4 hb = shA[c_prior_sorted[k + 1] - jbase];
    #pragma unroll
    for (int m = 0; m < PO; ++m) {
      float t = fmaf(nx[m], ha.x, ha.w); t = fmaf(ny[m], ha.y, t); t = fmaf(nz[m], ha.z, t);
      float u = fmaf(nx[m], hb.x, hb.w); u = fmaf(ny[m], hb.y, u); u = fmaf(nz[m], hb.z, u);
      bP[m] = f_min3(bP[m], t, u);
    }
  }
  if (k < pk1) {
    float4 ha = shA[c_prior_sorted[k] - jbase];
    #pragma unroll
    for (int m = 0; m < PO; ++m) {
      float t = fmaf(nx[m], ha.x, ha.w); t = fmaf(ny[m], ha.y, t); t = fmaf(nz[m], ha.z, t);
      bP[m] = fminf(bP[m], t);
    }
  }

  #pragma unroll
  for (int m = 0; m < PO; ++m) {
    if (!val[m]) continue;
    const size_t idx = (size_t)split * NKEY + (size_t)b * NO + (m * 256 + tid);
    keyR[idx] = bR[m];
    keyG[idx] = bG[m];
    priorK[idx] = bP[m];
  }
}

// ======================= dispatch 1b: hand -> obj NN =======================
// 768 blocks (32 b x 24 chunks), 128 thr, 6 hand pts/thread + 10-pt tail.
__global__ __launch_bounds__(128) void hand_nn(
    const float* __restrict__ recon, const float* __restrict__ gt,
    const float* __restrict__ obj,
    float* __restrict__ minHR, float* __restrict__ minHG)
{
  __shared__ float4 sO[HCS24];
  const int bid = blockIdx.x;
  const int tid = threadIdx.x;
  const int oc = bid % HC24;
  const int b  = bid / HC24;

  const float* Ob = obj + ((size_t)b * NO + oc * HCS24) * 3;
  for (int i = tid; i < HCS24; i += 128) {
    float x = Ob[3*i], y = Ob[3*i+1], z = Ob[3*i+2];
    sO[i] = make_float4(x, y, z, x*x + y*y + z*z);
  }
  __syncthreads();

  float nrx[PH], nry[PH], nrz[PH];
  float ngx[PH], ngy[PH], ngz[PH];
  #pragma unroll
  for (int m = 0; m < PH; ++m) {
    const int j = m * 128 + tid;                 // 0..767, always valid
    const float* rp = recon + ((size_t)b * NH + j) * 3;
    const float* gp = gt    + ((size_t)b * NH + j) * 3;
    nrx[m] = -2.f*rp[0]; nry[m] = -2.f*rp[1]; nrz[m] = -2.f*rp[2];
    ngx[m] = -2.f*gp[0]; ngy[m] = -2.f*gp[1]; ngz[m] = -2.f*gp[2];
  }

  float mR[PH], mG[PH];
  #pragma unroll
  for (int m = 0; m < PH; ++m) { mR[m] = 3.4e38f; mG[m] = 3.4e38f; }

  int k = 0;
  for (; k + 1 < HCS24; k += 2) {
    float4 o0 = sO[k], o1 = sO[k + 1];
    #pragma unroll
    for (int m = 0; m < PH; ++m) {
      float t0 = fmaf(nrx[m], o0.x, o0.w); t0 = fmaf(nry[m], o0.y, t0); t0 = fmaf(nrz[m], o0.z, t0);
      float t1 = fmaf(nrx[m], o1.x, o1.w); t1 = fmaf(nry[m], o1.y, t1); t1 = fmaf(nrz[m], o1.z, t1);
      mR[m] = f_min3(mR[m], t0, t1);
      float u0 = fmaf(ngx[m], o0.x, o0.w); u0 = fmaf(ngy[m], o0.y, u0); u0 = fmaf(ngz[m], o0.z, u0);
      float u1 = fmaf(ngx[m], o1.x, o1.w); u1 = fmaf(ngy[m], o1.y, u1); u1 = fmaf(ngz[m], o1.z, u1);
      mG[m] = f_min3(mG[m], u0, u1);
    }
  }
  { // HCS24=125 odd: single tail element
    float4 o0 = sO[HCS24 - 1];
    #pragma unroll
    for (int m = 0; m < PH; ++m) {
      float t0 = fmaf(nrx[m], o0.x, o0.w); t0 = fmaf(nry[m], o0.y, t0); t0 = fmaf(nrz[m], o0.z, t0);
      mR[m] = fminf(mR[m], t0);
      float u0 = fmaf(ngx[m], o0.x, o0.w); u0 = fmaf(ngy[m], o0.y, u0); u0 = fmaf(ngz[m], o0.z, u0);
      mG[m] = fminf(mG[m], u0);
    }
  }

  #pragma unroll
  for (int m = 0; m < PH; ++m) {
    const int j = m * 128 + tid;
    const size_t idx = (size_t)oc * NHT + (size_t)b * NH + j;
    minHR[idx] = mR[m];
    minHG[idx] = mG[m];
  }

  // tail: hand points 768..777 on one wave, rotated per block
  const int tw = bid & 1;
  if ((tid >> 6) == tw) {
    const int j3 = 768 + (tid & 63);
    const bool v3 = (j3 < NH);                   // lanes 0..9
    float rx=0.f,ry=0.f,rz=0.f,gx=0.f,gy=0.f,gz=0.f;
    if (v3) {
      const float* rp = recon + ((size_t)b * NH + j3) * 3;
      const float* gp = gt    + ((size_t)b * NH + j3) * 3;
      rx=rp[0];ry=rp[1];rz=rp[2]; gx=gp[0];gy=gp[1];gz=gp[2];
    }
    const float n3rx=-2.f*rx, n3ry=-2.f*ry, n3rz=-2.f*rz;
    const float n3gx=-2.f*gx, n3gy=-2.f*gy, n3gz=-2.f*gz;
    float m3R = 3.4e38f, m3G = 3.4e38f;
    int k3 = 0;
    for (; k3 + 1 < HCS24; k3 += 2) {
      float4 q0 = sO[k3], q1 = sO[k3 + 1];
      float t0 = fmaf(n3rx, q0.x, q0.w); t0 = fmaf(n3ry, q0.y, t0); t0 = fmaf(n3rz, q0.z, t0);
      float t1 = fmaf(n3rx, q1.x, q1.w); t1 = fmaf(n3ry, q1.y, t1); t1 = fmaf(n3rz, q1.z, t1);
      m3R = f_min3(m3R, t0, t1);
      float u0 = fmaf(n3gx, q0.x, q0.w); u0 = fmaf(n3gy, q0.y, u0); u0 = fmaf(n3gz, q0.z, u0);
      float u1 = fmaf(n3gx, q1.x, q1.w); u1 = fmaf(n3gy, q1.y, u1); u1 = fmaf(n3gz, q1.z, u1);
      m3G = f_min3(m3G, u0, u1);
    }
    {
      float4 q0 = sO[HCS24 - 1];
      float t0 = fmaf(n3rx, q0.x, q0.w); t0 = fmaf(n3ry, q0.y, t0); t0 = fmaf(n3rz, q0.z, t0);
      m3R = fminf(m3R, t0);
      float u0 = fmaf(n3gx, q0.x, q0.w); u0 = fmaf(n3gy, q0.y, u0); u0 = fmaf(n3gz, q0.z, u0);
      m3G = fminf(m3G, u0);
    }
    if (v3) {
      const size_t idx = (size_t)oc * NHT + (size_t)b * NH + j3;
      minHR[idx] = m3R;
      minHG[idx] = m3G;
    }
  }
}

// ======================= dispatch 2: mega2 =======================
template<int JS, int HCn>
__global__ __launch_bounds__(256) void mega2t(
    const float* __restrict__ recon, const float* __restrict__ gt,
    const float* __restrict__ rnorm, const float* __restrict__ gnorm,
    const float* __restrict__ obj,
    const float* __restrict__ mean, const float* __restrict__ logv,
    const float* __restrict__ vw,
    const float* __restrict__ keyR, const float* __restrict__ keyG,
    const float* __restrict__ priorK,
    const float* __restrict__ minHR, const float* __restrict__ minHG,
    float* __restrict__ accs, float* __restrict__ out)
{
  __shared__ float red[4][5];
  const int bid = blockIdx.x;
  const int tid = threadIdx.x;
  const int lane = tid & 63, wv = tid >> 6;

  if (bid < FIN_OBJ_BLKS) {
    const int b = bid / T2;
    const int tile = bid % T2;
    const int o = tile * 256 + tid;
    float penetr = 0.f, nptsv = 0.f, contactv = 0.f, consistv = 0.f, lossov = 0.f;
    if (o < NO) {
      const float* op = obj + ((size_t)b * NO + o) * 3;
      const float ox = op[0], oy = op[1], oz = op[2];
      const float o2 = ox*ox + oy*oy + oz*oz;
      const size_t base = (size_t)b * NO + o;

      float kR = 3.4e38f, kG = 3.4e38f, bP = 3.4e38f;
      #pragma unroll
      for (int s = 0; s < JS; ++s) {
        kR = fminf(kR, keyR[(size_t)s * NKEY + base]);
        kG = fminf(kG, keyG[(size_t)s * NKEY + base]);
        bP = fminf(bP, priorK[(size_t)s * NKEY + base]);
      }
      uint32 kRb = __float_as_uint(kR), kGb = __float_as_uint(kG);
      int idxR = (int)(kRb & 0x3FFu), idxG = (int)(kGb & 0x3FFu);
      float d2R = fmaxf(__uint_as_float(kRb & 0xFFFFFC00u) + o2, 0.f);
      float d2G = fmaxf(__uint_as_float(kGb & 0xFFFFFC00u) + o2, 0.f);
      float d2P = fmaxf(bP + o2, 0.f);

      const float* hR = recon + ((size_t)b * NH + idxR) * 3;
      const float* nR = rnorm + ((size_t)b * NH + idxR) * 3;
      float dotR = (ox - hR[0]) * nR[0] + (oy - hR[1]) * nR[1] + (oz - hR[2]) * nR[2];
      const float* hG = gt + ((size_t)b * NH + idxG) * 3;
      const float* nG = gnorm + ((size_t)b * NH + idxG) * 3;
      float dotG = (ox - hG[0]) * nG[0] + (oy - hG[1]) * nG[1] + (oz - hG[2]) * nG[2];

      float sgnR = (dotR > 0.f) ? 1.f : ((dotR < 0.f) ? -1.f : 0.f);
      float sgnG = (dotG > 0.f) ? 1.f : ((dotG < 0.f) ? -1.f : 0.f);
      float sR_ = sqrtf(d2R), sG_ = sqrtf(d2G);
      float o2h = sR_ * sgnR, o2hg = sG_ * sgnG;

      bool interior = dotR < 0.f;
      bool cmap = sG_ < 0.005f;
      bool rcmap = sR_ < 0.005f;

      penetr   = interior ? d2R : 0.f;
      nptsv    = cmap ? 1.f : 0.f;
      contactv = cmap ? d2P : 0.f;
      consistv = (cmap && rcmap) ? 1.f : 0.f;
      float w = (o2h < 0.f) ? 1.5f
              : (((o2hg < 0.01f) && (o2hg > -0.005f)) ? 1.f : 0.1f);
      lossov = fabsf(o2h - o2hg) * w;
    }

    float vals[5] = {penetr, nptsv, contactv, consistv, lossov};
    #pragma unroll
    for (int q = 0; q < 5; ++q) {
      float s = wave_sum(vals[q]);
      if (lane == 0) red[wv][q] = s;
    }
    __syncthreads();
    if (tid < 5) {
      float s = red[0][tid] + red[1][tid] + red[2][tid] + red[3][tid];
      atomicAdd(&accs[tid * ACC_STRIDE], s);
    }
  } else {
    const int t = (bid - FIN_OBJ_BLKS) * 256 + tid;
    float lossh = 0.f, rsum = 0.f, ksum = 0.f;
    if (t < NB * NH) {
      const float* rp = recon + (size_t)t * 3;
      const float* gp = gt + (size_t)t * 3;
      float rx = rp[0], ry = rp[1], rz = rp[2];
      float gx = gp[0], gy = gp[1], gz = gp[2];
      float d0 = rx - gx, d1 = ry - gy, d2 = rz - gz;
      rsum = d0*d0 + d1*d1 + d2*d2;

      float mRt = 3.4e38f, mGt = 3.4e38f;
      #pragma unroll
      for (int c = 0; c < HCn; ++c) {
        mRt = fminf(mRt, minHR[(size_t)c * NHT + t]);
        mGt = fminf(mGt, minHG[(size_t)c * NHT + t]);
      }
      float r2 = rx*rx + ry*ry + rz*rz;
      float g2 = gx*gx + gy*gy + gz*gz;
      float d2Rh = fmaxf(mRt + r2, 0.f);
      float d2Gh = fmaxf(mGt + g2, 0.f);
      int j = t % NH;
      lossh = fabsf(sqrtf(d2Rh) - sqrtf(d2Gh)) * powf(vw[j], 0.4f);
    }
    if (t < NB * NZ) {
      float m = mean[t], lv = logv[t];
      ksum = 1.f + lv - m * m - expf(lv);
    }
    float vals[3] = {lossh, rsum, ksum};
    #pragma unroll
    for (int q = 0; q < 3; ++q) {
      float s = wave_sum(vals[q]);
      if (lane == 0) red[wv][q] = s;
    }
    __syncthreads();
    if (tid < 3) {
      float s = red[0][tid] + red[1][tid] + red[2][tid] + red[3][tid];
      atomicAdd(&accs[(5 + tid) * ACC_STRIDE], s);
    }
  }

  // ---- fused final: last block combines ----
  __syncthreads();
  if (tid == 0) {
    __threadfence();
    int* cnt = (int*)(accs + 8 * ACC_STRIDE);
    int old = atomicAdd(cnt, 1);
    if (old == FIN_BLKS - 1) {
      float a[8];
      #pragma unroll
      for (int q = 0; q < 8; ++q) a[q] = atomicAdd(&accs[q * ACC_STRIDE], 0.0f);
      const float recon_loss = a[6] / (float)NB;
      const float kld = -0.5f * a[7] / (float)NB * 10.f;
      const float penetr = 100.f * a[0] / (float)NB;
      const float npts = a[1];
      const float contact = (npts > 0.f) ? (3000.f * a[2] / ((float)NB * npts)) : 0.f;
      const float consistency = -5.f * a[3] / (npts + 0.0001f);
      const float lossh = 35.f * (1.f - 0.005f) * (a[5] / (float)(NB * NH));
      const float losso = 30.f * (1.f - 0.005f) * (a[4] / (float)(NB * NO));
      out[0] = recon_loss + 0.1f * kld + 1000.f * penetr + 10.f * contact
             + 10.f * consistency + lossh + losso;
    }
  }
}

// =========================== PATH C (tiny ws fallback) ===========================
__global__ __launch_bounds__(256) void obj_mono(
    const float* __restrict__ recon, const float* __restrict__ gt,
    const float* __restrict__ rnorm, const float* __restrict__ gnorm,
    const float* __restrict__ obj, float* __restrict__ accs)
{
  __shared__ float4 sR[NH];
  __shared__ float4 sG[NH];
  __shared__ float red[4][5];
  const int b = blockIdx.x / 12;
  const int tile = blockIdx.x % 12;
  const int tid = threadIdx.x;
  for (int i = tid; i < NH; i += 256) {
    const float* p = recon + ((size_t)b * NH + i) * 3;
    float x = p[0], y = p[1], z = p[2];
    sR[i] = make_float4(x, y, z, x*x + y*y + z*z);
    const float* q = gt + ((size_t)b * NH + i) * 3;
    float gx = q[0], gy = q[1], gz = q[2];
    sG[i] = make_float4(gx, gy, gz, gx*gx + gy*gy + gz*gz);
  }
  __syncthreads();
  const int o = tile * 256 + tid;
  float penetr = 0.f, nptsv = 0.f, contactv = 0.f, consistv = 0.f, lossov = 0.f;
  if (o < NO) {
    const float* op = obj + ((size_t)b * NO + o) * 3;
    const float ox = op[0], oy = op[1], oz = op[2];
    const float nx = -2.f*ox, ny = -2.f*oy, nz = -2.f*oz;
    const float o2 = ox*ox + oy*oy + oz*oz;
    float bR = 3.4e38f, bG = 3.4e38f; int iR = 0, iG = 0;
    for (int i = 0; i < NH; ++i) {
      float4 h = sR[i];
      float t = fmaf(nx, h.x, h.w); t = fmaf(ny, h.y, t); t = fmaf(nz, h.z, t);
      if (t < bR) { bR = t; iR = i; }
      float4 g = sG[i];
      float u = fmaf(nx, g.x, g.w); u = fmaf(ny, g.y, u); u = fmaf(nz, g.z, u);
      if (u < bG) { bG = u; iG = i; }
    }
    float bP = 3.4e38f;
    for (int k = 0; k < NP; ++k) {
      float4 h = sR[c_prior[k]];
      float t = fmaf(nx, h.x, h.w); t = fmaf(ny, h.y, t); t = fmaf(nz, h.z, t);
      bP = fminf(bP, t);
    }
    float d2R = fmaxf(bR + o2, 0.f);
    float d2G = fmaxf(bG + o2, 0.f);
    float d2P = fmaxf(bP + o2, 0.f);
    float4 hR = sR[iR];
    const float* nR = rnorm + ((size_t)b * NH + iR) * 3;
    float dotR = (ox-hR.x)*nR[0] + (oy-hR.y)*nR[1] + (oz-hR.z)*nR[2];
    float4 hG = sG[iG];
    const float* nG = gnorm + ((size_t)b * NH + iG) * 3;
    float dotG = (ox-hG.x)*nG[0] + (oy-hG.y)*nG[1] + (oz-hG.z)*nG[2];
    float sgnR = (dotR > 0.f) ? 1.f : ((dotR < 0.f) ? -1.f : 0.f);
    float sgnG = (dotG > 0.f) ? 1.f : ((dotG < 0.f) ? -1.f : 0.f);
    float sR_ = sqrtf(d2R), sG_ = sqrtf(d2G);
    float o2h = sR_*sgnR, o2hg = sG_*sgnG;
    bool interior = dotR < 0.f;
    bool cmap = sG_ < 0.005f, rcmap = sR_ < 0.005f;
    penetr = interior ? d2R : 0.f;
    nptsv = cmap ? 1.f : 0.f;
    contactv = cmap ? d2P : 0.f;
    consistv = (cmap && rcmap) ? 1.f : 0.f;
    float w = (o2h < 0.f) ? 1.5f : (((o2hg < 0.01f) && (o2hg > -0.005f)) ? 1.f : 0.1f);
    lossov = fabsf(o2h - o2hg) * w;
  }
  float vals[5] = {penetr, nptsv, contactv, consistv, lossov};
  const int lane = tid & 63, wv = tid >> 6;
  for (int q = 0; q < 5; ++q) {
    float s = wave_sum(vals[q]);
    if (lane == 0) red[wv][q] = s;
  }
  __syncthreads();
  if (tid < 5) {
    float s = red[0][tid] + red[1][tid] + red[2][tid] + red[3][tid];
    atomicAdd(&accs[tid * ACC_STRIDE], s);
  }
}

__global__ __launch_bounds__(256) void hand_full(
    const float* __restrict__ recon, const float* __restrict__ gt,
    const float* __restrict__ obj, const float* __restrict__ vw,
    float* __restrict__ accs)
{
  __shared__ float4 sO[500];
  __shared__ float red[4];
  const int b = blockIdx.x >> 2;
  const int j = ((blockIdx.x & 3) << 8) + threadIdx.x;
  const bool valid = j < NH;
  float rx=0,ry=0,rz=0,gx=0,gy=0,gz=0;
  if (valid) {
    const float* rp = recon + ((size_t)b * NH + j) * 3;
    const float* gp = gt + ((size_t)b * NH + j) * 3;
    rx=rp[0];ry=rp[1];rz=rp[2]; gx=gp[0];gy=gp[1];gz=gp[2];
  }
  const float nrx=-2.f*rx, nry=-2.f*ry, nrz=-2.f*rz;
  const float ngx=-2.f*gx, ngy=-2.f*gy, ngz=-2.f*gz;
  const float r2 = rx*rx+ry*ry+rz*rz, g2 = gx*gx+gy*gy+gz*gz;
  float mR = 3.4e38f, mG = 3.4e38f;
  for (int oc = 0; oc < 6; ++oc) {
    __syncthreads();
    const float* Ob = obj + ((size_t)b * NO + oc * 500) * 3;
    for (int i = threadIdx.x; i < 500; i += 256) {
      float x = Ob[3*i], y = Ob[3*i+1], z = Ob[3*i+2];
      sO[i] = make_float4(x, y, z, x*x + y*y + z*z);
    }
    __syncthreads();
    if (valid) {
      for (int k = 0; k < 500; ++k) {
        float4 o4 = sO[k];
        float t = fmaf(nrx,o4.x,o4.w); t = fmaf(nry,o4.y,t); t = fmaf(nrz,o4.z,t);
        mR = fminf(mR, t);
        float u = fmaf(ngx,o4.x,o4.w); u = fmaf(ngy,o4.y,u); u = fmaf(ngz,o4.z,u);
        mG = fminf(mG, u);
      }
    }
  }
  float lossh = valid ? fabsf(sqrtf(fmaxf(mR+r2,0.f)) - sqrtf(fmaxf(mG+g2,0.f))) * powf(vw[j], 0.4f) : 0.f;
  const int lane = threadIdx.x & 63, wv = threadIdx.x >> 6;
  float s = wave_sum(lossh);
  if (lane == 0) red[wv] = s;
  __syncthreads();
  if (threadIdx.x == 0) atomicAdd(&accs[5 * ACC_STRIDE], red[0]+red[1]+red[2]+red[3]);
}

__global__ __launch_bounds__(256) void tail_nomins(
    const float* __restrict__ recon, const float* __restrict__ gt,
    const float* __restrict__ mean, const float* __restrict__ logv,
    float* __restrict__ accs)
{
  __shared__ float red[4][2];
  const int t = blockIdx.x * 256 + threadIdx.x;
  float rsum = 0.f, ksum = 0.f;
  if (t < NB * NH) {
    const float* rp = recon + (size_t)t * 3;
    const float* gp = gt + (size_t)t * 3;
    float d0 = rp[0]-gp[0], d1 = rp[1]-gp[1], d2 = rp[2]-gp[2];
    rsum = d0*d0 + d1*d1 + d2*d2;
  }
  if (t < NB * NZ) {
    float m = mean[t], lv = logv[t];
    ksum = 1.f + lv - m*m - expf(lv);
  }
  float vals[2] = {rsum, ksum};
  const int lane = threadIdx.x & 63, wv = threadIdx.x >> 6;
  for (int q = 0; q < 2; ++q) {
    float s = wave_sum(vals[q]);
    if (lane == 0) red[wv][q] = s;
  }
  __syncthreads();
  if (threadIdx.x < 2) {
    float s = red[0][threadIdx.x] + red[1][threadIdx.x] + red[2][threadIdx.x] + red[3][threadIdx.x];
    atomicAdd(&accs[(6 + threadIdx.x) * ACC_STRIDE], s);
  }
}

__global__ void init_small(float* accs) {
  int t = threadIdx.x;
  accs[t] = 0.0f;
  accs[t + 256] = 0.0f;
}

__global__ void final_fb(const float* __restrict__ a, float* __restrict__ out) {
  const float recon_loss = a[6 * ACC_STRIDE] / (float)NB;
  const float kld = -0.5f * a[7 * ACC_STRIDE] / (float)NB * 10.f;
  const float penetr = 100.f * a[0] / (float)NB;
  const float npts = a[1 * ACC_STRIDE];
  const float contact = (npts > 0.f) ? (3000.f * a[2 * ACC_STRIDE] / ((float)NB * npts)) : 0.f;
  const float consistency = -5.f * a[3 * ACC_STRIDE] / (npts + 0.0001f);
  const float lossh = 35.f * (1.f - 0.005f) * (a[5 * ACC_STRIDE] / (float)(NB * NH));
  const float losso = 30.f * (1.f - 0.005f) * (a[4 * ACC_STRIDE] / (float)(NB * NO));
  out[0] = recon_loss + 0.1f*kld + 1000.f*penetr + 10.f*contact + 10.f*consistency + lossh + losso;
}

extern "C" void kernel_launch(void* const* d_in, const int* in_sizes, int n_in,
                              void* d_out, int out_size, void* d_ws, size_t ws_size,
                              hipStream_t stream) {
  const float* recon = (const float*)d_in[0];
  const float* gt    = (const float*)d_in[1];
  const float* rnorm = (const float*)d_in[2];
  const float* gnorm = (const float*)d_in[3];
  const float* obj   = (const float*)d_in[4];
  const float* mean  = (const float*)d_in[5];
  const float* logv  = (const float*)d_in[6];
  const float* vw    = (const float*)d_in[7];
  float* out = (float*)d_out;

  // ws: padded accs[512] @0 (2048B) | keyR[8N] keyG[8N] priorK[8N]
  //     minHR[24H] minHG[24H]
  float* accs = (float*)d_ws;
  float* base = (float*)((char*)d_ws + ACC_FLOATS * sizeof(float));

  const size_t needed = ACC_FLOATS * sizeof(float)
                      + (3ull * JS8 * NKEY + 2ull * HC24 * NHT) * sizeof(float);

  if (ws_size >= needed) {
    float* keyR   = base;
    float* keyG   = keyR + (size_t)JS8 * NKEY;
    float* priorK = keyG + (size_t)JS8 * NKEY;
    float* minHR  = priorK + (size_t)JS8 * NKEY;
    float* minHG  = minHR + (size_t)HC24 * NHT;
    obj_nn<<<NB * JS8, 256, 0, stream>>>(
        recon, gt, obj, keyR, keyG, priorK, accs);
    hand_nn<<<NB * HC24, 128, 0, stream>>>(
        recon, gt, obj, minHR, minHG);
    mega2t<JS8, HC24><<<FIN_BLKS, 256, 0, stream>>>(
        recon, gt, rnorm, gnorm, obj, mean, logv, vw,
        keyR, keyG, priorK, minHR, minHG, accs, out);
  } else {
    init_small<<<1, 256, 0, stream>>>(accs);
    obj_mono<<<NB * 12, 256, 0, stream>>>(recon, gt, rnorm, gnorm, obj, accs);
    hand_full<<<NB * 4, 256, 0, stream>>>(recon, gt, obj, vw, accs);
    tail_nomins<<<(NB * NH + 255) / 256, 256, 0, stream>>>(recon, gt, mean, logv, accs);
    final_fb<<<1, 1, 0, stream>>>(accs, out);
  }
}

// Round 5
// 121.883 us; speedup vs baseline: 1.1656x; 1.1656x over previous
//
#include <hip/hip_runtime.h>
#include <math.h>

// GraspCVAE loss, MI355X — round 13.
// R12 post-mortem: -23us regression was the PACKAGING (3 serialized
// dispatches; obj_nn at 1 block/CU with nothing to overlap), not the lever.
// R13 fuses the ds_read amortization INTO R11's proven single mega1 dispatch:
//   * obj half: P_OBJ 6 (tiles 3->2) -> obj wave-reads x2/3 (602K->401K),
//     ~70 persistent VGPR (no R12 PO=12 spill risk).
//   * hand half: two independent 128-thr groups per block, each stages+scans
//     its OWN chunk (j/thread 3->6) -> hand wave-reads x1/2 (384K->192K).
//   * grid 512 obj + 384 hand = 896 mixed blocks, ONE dispatch; mega2 and
//     workspace layout identical to R11 (JS=8, HC=24, padded accs).
// Total ds_read_b128: 986K -> 593K (-40%) at identical FMA count.
// Predict: mega1 42 -> ~30, total 118.8 -> ~105-110. If neutral: read-count
// theory dead -> pivot to mega2 / harness floor.

#define NB 32
#define NH 778
#define NO 3000
#define NZ 64
#define NP 204

#define JS8 8
#define JC8 98                        // ceil(778/8)
#define PO 6                          // obj pts per thread
#define OT 2                          // obj tiles
#define OT_PTS 1536                   // pts per tile (6*256)
#define HC24 24
#define HCS 125                       // 3000/24
#define PH 6                          // hand pts per thread (6*128=768)

#define OBJ_B (NB * OT * JS8)         // 512
#define HAND_B (NB * 12)              // 384 (2 chunks per block)

#define T2 12                         // mega2 obj tiles (256 pts)
#define FIN_OBJ_BLKS (NB * T2)                // 384
#define FIN_TAIL_BLKS ((NB * NH + 255) / 256) // 98
#define FIN_BLKS (FIN_OBJ_BLKS + FIN_TAIL_BLKS) // 482

#define NKEY (NB * NO)                // 96000
#define NHT  (NB * NH)                // 24896

// accumulator padding: each logical slot q lives at accs[q*ACC_STRIDE]
#define ACC_STRIDE 32                 // 32 floats = 128 B = own cache line
#define ACC_FLOATS 512                // 16 slots * 32

typedef unsigned int uint32;

// original order (used by PATH C)
__device__ __constant__ int c_prior[NP] = {
  697,698,699,700,712,713,714,715,737,738,739,740,741,743,744,745,746,748,749,750,
  753,754,755,756,757,758,759,760,761,762,763,764,765,766,767,768,
  46,47,48,49,164,165,166,167,194,195,223,237,238,280,281,298,301,317,320,323,
  324,325,326,327,328,329,330,331,332,333,340,341,342,343,344,345,346,347,348,349,
  350,351,352,353,354,355,
  356,357,358,359,375,376,386,387,396,397,402,403,413,429,433,434,435,436,437,438,
  439,440,441,442,443,444,452,453,454,455,456,459,460,461,462,463,464,465,466,467,
  468,469,470,471,484,485,486,496,497,506,507,513,514,524,545,546,547,548,549,550,
  551,552,553,555,563,564,565,566,567,570,572,573,574,575,576,577,578,
  580,581,582,583,600,601,602,614,615,624,625,630,631,641,663,664,665,666,667,668,
  670,672,680,681,682,683,684,686,687,688,689,690,691,692,693,694,695,
  73,96,98,99,772,774,775,777
};

// globally ascending sorted prior list (usable for ANY contiguous j-split)
__device__ __constant__ int c_prior_sorted[NP] = {
  46,47,48,49,73,96,98,99,164,165,166,167,194,
  195,223,237,238,280,281,298,301,317,320,323,324,325,326,327,328,329,330,331,
  332,333,340,341,342,343,344,345,346,347,348,349,350,351,352,353,354,355,356,
  357,358,359,375,376,386,387,
  396,397,402,403,413,429,433,434,435,436,437,438,439,440,441,442,443,444,452,
  453,454,455,456,459,460,461,462,463,464,465,466,467,468,469,470,471,484,485,
  486,496,497,506,507,513,514,524,545,546,547,548,549,550,551,552,553,555,563,
  564,565,566,567,570,572,573,574,575,576,577,578,580,581,582,583,
  600,601,602,614,615,624,625,630,631,641,663,664,665,666,667,668,670,672,680,
  681,682,683,684,686,687,688,689,690,691,692,693,694,695,697,698,699,700,712,
  713,714,715,737,738,739,740,741,743,744,745,746,748,749,750,753,754,755,756,
  757,758,759,760,761,762,763,764,765,766,767,768,772,774,775,777
};
// position ranges in c_prior_sorted for j in [s*98, (s+1)*98)
__device__ __constant__ int c_psplit8[9] = {0, 6, 14, 19, 58, 97, 131, 154, 204};

__device__ inline float wave_sum(float v) {
  v += __shfl_down(v, 32);
  v += __shfl_down(v, 16);
  v += __shfl_down(v, 8);
  v += __shfl_down(v, 4);
  v += __shfl_down(v, 2);
  v += __shfl_down(v, 1);
  return v;
}

// forced 3-operand VALU ops (R9: verified correct)
__device__ __forceinline__ float f_min3(float a, float b, float c) {
  float r;
  asm("v_min3_f32 %0, %1, %2, %3" : "=v"(r) : "v"(a), "v"(b), "v"(c));
  return r;
}
__device__ __forceinline__ float f_packao(float t, int j, uint32 mask) {
  float r;
  asm("v_and_or_b32 %0, %1, %2, %3" : "=v"(r) : "v"(t), "s"(mask), "v"(j));
  return r;
}

// ======================= dispatch 1: fused mega1 =======================
// blocks [0, 512): obj->hand NN (tile x split), PO=6
// blocks [512, 896): hand->obj NN, 2 independent 128-thr chunk-groups
__global__ __launch_bounds__(256) void mega1f(
    const float* __restrict__ recon, const float* __restrict__ gt,
    const float* __restrict__ obj,
    float* __restrict__ keyR, float* __restrict__ keyG,
    float* __restrict__ priorK,
    float* __restrict__ minHR, float* __restrict__ minHG,
    float* __restrict__ accs)
{
  const int bid = blockIdx.x;
  const int tid = threadIdx.x;
  const uint32 KMASK = 0xFFFFFC00u;

  if (bid == 0) {  // zero padded accumulator region (consumed after boundary)
    accs[tid] = 0.0f;
    accs[tid + 256] = 0.0f;
  }

  if (bid < OBJ_B) {
    // ---- obj -> hand NN (j-split 8, 2 tiles, PO=6) + partial prior-NN ----
    __shared__ float4 shA[JC8];   // recon split
    __shared__ float4 shB[JC8];   // gt split
    const int b     = bid / (OT * JS8);
    const int rem   = bid % (OT * JS8);
    const int tile  = rem / JS8;
    const int split = rem % JS8;
    const int jbase = split * JC8;
    const int jcnt  = (NH - jbase < JC8) ? (NH - jbase) : JC8;  // 98 or 92

    for (int i = tid; i < jcnt; i += 256) {
      const float* p = recon + ((size_t)b * NH + jbase + i) * 3;
      float x = p[0], y = p[1], z = p[2];
      shA[i] = make_float4(x, y, z, x*x + y*y + z*z);
      const float* q = gt + ((size_t)b * NH + jbase + i) * 3;
      float gx = q[0], gy = q[1], gz = q[2];
      shB[i] = make_float4(gx, gy, gz, gx*gx + gy*gy + gz*gz);
    }
    __syncthreads();

    float nx[PO], ny[PO], nz[PO];
    bool val[PO];
    #pragma unroll
    for (int m = 0; m < PO; ++m) {
      const int o = tile * OT_PTS + m * 256 + tid;
      val[m] = (o < NO);
      float x = 0.f, y = 0.f, z = 0.f;
      if (val[m]) {
        const float* op = obj + ((size_t)b * NO + o) * 3;
        x = op[0]; y = op[1]; z = op[2];
      }
      nx[m] = -2.f * x; ny[m] = -2.f * y; nz[m] = -2.f * z;
    }

    float bR[PO], bG[PO], bP[PO];
    #pragma unroll
    for (int m = 0; m < PO; ++m) { bR[m] = 3.4e38f; bG[m] = 3.4e38f; bP[m] = 3.4e38f; }

#define RSTEP(hh0, hh1, jj0, jj1) \
    { _Pragma("unroll") for (int m = 0; m < PO; ++m) { \
        float t0 = fmaf(nx[m], hh0.x, hh0.w); t0 = fmaf(ny[m], hh0.y, t0); t0 = fmaf(nz[m], hh0.z, t0); \
        float t1 = fmaf(nx[m], hh1.x, hh1.w); t1 = fmaf(ny[m], hh1.y, t1); t1 = fmaf(nz[m], hh1.z, t1); \
        bR[m] = f_min3(bR[m], f_packao(t0, jj0, KMASK), f_packao(t1, jj1, KMASK)); } }
#define GSTEP(gg0, gg1, jj0, jj1) \
    { _Pragma("unroll") for (int m = 0; m < PO; ++m) { \
        float u0 = fmaf(nx[m], gg0.x, gg0.w); u0 = fmaf(ny[m], gg0.y, u0); u0 = fmaf(nz[m], gg0.z, u0); \
        float u1 = fmaf(nx[m], gg1.x, gg1.w); u1 = fmaf(ny[m], gg1.y, u1); u1 = fmaf(nz[m], gg1.z, u1); \
        bG[m] = f_min3(bG[m], f_packao(u0, jj0, KMASK), f_packao(u1, jj1, KMASK)); } }

    // interleaved prefetch (R10-proven): each LDS read pair covered by VALU
    float4 h0 = shA[0], h1 = shA[1];
    int i = 0;
    for (; i + 3 < jcnt; i += 2) {
      float4 g0 = shB[i], g1 = shB[i + 1];       // issue G loads
      RSTEP(h0, h1, jbase + i, jbase + i + 1);   // compute R (covers G)
      float4 hn0 = shA[i + 2], hn1 = shA[i + 3]; // issue next A loads
      GSTEP(g0, g1, jbase + i, jbase + i + 1);   // compute G (covers A)
      h0 = hn0; h1 = hn1;
    }
    { // last preloaded pair (jcnt is even: 98 or 92)
      float4 g0 = shB[i], g1 = shB[i + 1];
      RSTEP(h0, h1, jbase + i, jbase + i + 1);
      GSTEP(g0, g1, jbase + i, jbase + i + 1);
      i += 2;
    }
    for (; i < jcnt; ++i) {      // safety (never triggers for 98/92)
      float4 hh = shA[i], gg = shB[i];
      #pragma unroll
      for (int m = 0; m < PO; ++m) {
        float t0 = fmaf(nx[m], hh.x, hh.w); t0 = fmaf(ny[m], hh.y, t0); t0 = fmaf(nz[m], hh.z, t0);
        bR[m] = fminf(bR[m], f_packao(t0, jbase + i, KMASK));
        float u0 = fmaf(nx[m], gg.x, gg.w); u0 = fmaf(ny[m], gg.y, u0); u0 = fmaf(nz[m], gg.z, u0);
        bG[m] = fminf(bG[m], f_packao(u0, jbase + i, KMASK));
      }
    }
#undef RSTEP
#undef GSTEP

    // partial prior-NN over this split's prior members (candidates in shA)
    const int pk0 = c_psplit8[split], pk1 = c_psplit8[split + 1];
    int k = pk0;
    for (; k + 1 < pk1; k += 2) {
      float4 ha = shA[c_prior_sorted[k] - jbase];
      float4 hb = shA[c_prior_sorted[k + 1] - jbase];
      #pragma unroll
      for (int m = 0; m < PO; ++m) {
        float t = fmaf(nx[m], ha.x, ha.w); t = fmaf(ny[m], ha.y, t); t = fmaf(nz[m], ha.z, t);
        float u = fmaf(nx[m], hb.x, hb.w); u = fmaf(ny[m], hb.y, u); u = fmaf(nz[m], hb.z, u);
        bP[m] = f_min3(bP[m], t, u);
      }
    }
    if (k < pk1) {
      float4 ha = shA[c_prior_sorted[k] - jbase];
      #pragma unroll
      for (int m = 0; m < PO; ++m) {
        float t = fmaf(nx[m], ha.x, ha.w); t = fmaf(ny[m], ha.y, t); t = fmaf(nz[m], ha.z, t);
        bP[m] = fminf(bP[m], t);
      }
    }

    #pragma unroll
    for (int m = 0; m < PO; ++m) {
      if (!val[m]) continue;
      const int o = tile * OT_PTS + m * 256 + tid;
      const size_t idx = (size_t)split * NKEY + (size_t)b * NO + o;
      keyR[idx] = bR[m];
      keyG[idx] = bG[m];
      priorK[idx] = bP[m];
    }
  } else {
    // ---- hand -> obj NN: two independent 128-thr groups, one chunk each ----
    __shared__ float4 sO2[2][HCS];
    const int bid2 = bid - OBJ_B;
    const int b     = bid2 / 12;
    const int cpair = bid2 % 12;
    const int g     = tid >> 7;          // group 0/1
    const int ltid  = tid & 127;
    const int chunk = cpair * 2 + g;     // [0, 24)

    const float* Ob = obj + ((size_t)b * NO + chunk * HCS) * 3;
    for (int i2 = ltid; i2 < HCS; i2 += 128) {
      float x = Ob[3*i2], y = Ob[3*i2+1], z = Ob[3*i2+2];
      sO2[g][i2] = make_float4(x, y, z, x*x + y*y + z*z);
    }
    __syncthreads();

    float nrx[PH], nry[PH], nrz[PH];
    float ngx[PH], ngy[PH], ngz[PH];
    #pragma unroll
    for (int m = 0; m < PH; ++m) {
      const int j = m * 128 + ltid;                // 0..767, always valid
      const float* rp = recon + ((size_t)b * NH + j) * 3;
      const float* gp = gt    + ((size_t)b * NH + j) * 3;
      nrx[m] = -2.f*rp[0]; nry[m] = -2.f*rp[1]; nrz[m] = -2.f*rp[2];
      ngx[m] = -2.f*gp[0]; ngy[m] = -2.f*gp[1]; ngz[m] = -2.f*gp[2];
    }

    float mR[PH], mG[PH];
    #pragma unroll
    for (int m = 0; m < PH; ++m) { mR[m] = 3.4e38f; mG[m] = 3.4e38f; }

    int k2 = 0;
    for (; k2 + 1 < HCS; k2 += 2) {
      float4 o0 = sO2[g][k2], o1 = sO2[g][k2 + 1];
      #pragma unroll
      for (int m = 0; m < PH; ++m) {
        float t0 = fmaf(nrx[m], o0.x, o0.w); t0 = fmaf(nry[m], o0.y, t0); t0 = fmaf(nrz[m], o0.z, t0);
        float t1 = fmaf(nrx[m], o1.x, o1.w); t1 = fmaf(nry[m], o1.y, t1); t1 = fmaf(nrz[m], o1.z, t1);
        mR[m] = f_min3(mR[m], t0, t1);
        float u0 = fmaf(ngx[m], o0.x, o0.w); u0 = fmaf(ngy[m], o0.y, u0); u0 = fmaf(ngz[m], o0.z, u0);
        float u1 = fmaf(ngx[m], o1.x, o1.w); u1 = fmaf(ngy[m], o1.y, u1); u1 = fmaf(ngz[m], o1.z, u1);
        mG[m] = f_min3(mG[m], u0, u1);
      }
    }
    { // HCS=125 odd: single tail element
      float4 o0 = sO2[g][HCS - 1];
      #pragma unroll
      for (int m = 0; m < PH; ++m) {
        float t0 = fmaf(nrx[m], o0.x, o0.w); t0 = fmaf(nry[m], o0.y, t0); t0 = fmaf(nrz[m], o0.z, t0);
        mR[m] = fminf(mR[m], t0);
        float u0 = fmaf(ngx[m], o0.x, o0.w); u0 = fmaf(ngy[m], o0.y, u0); u0 = fmaf(ngz[m], o0.z, u0);
        mG[m] = fminf(mG[m], u0);
      }
    }

    #pragma unroll
    for (int m = 0; m < PH; ++m) {
      const int j = m * 128 + ltid;
      const size_t idx = (size_t)chunk * NHT + (size_t)b * NH + j;
      minHR[idx] = mR[m];
      minHG[idx] = mG[m];
    }

    // tail: hand points 768..777 vs this group's chunk; one wave per group,
    // rotated per block to balance SIMD load
    const int lw = (tid >> 6) & 1;       // local wave within group
    if (lw == (bid2 & 1)) {
      const int j3 = 768 + (tid & 63);
      const bool v3 = (j3 < NH);         // lanes 0..9
      float rx=0.f,ry=0.f,rz=0.f,gx=0.f,gy=0.f,gz=0.f;
      if (v3) {
        const float* rp = recon + ((size_t)b * NH + j3) * 3;
        const float* gp = gt    + ((size_t)b * NH + j3) * 3;
        rx=rp[0];ry=rp[1];rz=rp[2]; gx=gp[0];gy=gp[1];gz=gp[2];
      }
      const float n3rx=-2.f*rx, n3ry=-2.f*ry, n3rz=-2.f*rz;
      const float n3gx=-2.f*gx, n3gy=-2.f*gy, n3gz=-2.f*gz;
      float m3R = 3.4e38f, m3G = 3.4e38f;
      int k3 = 0;
      for (; k3 + 1 < HCS; k3 += 2) {
        float4 q0 = sO2[g][k3], q1 = sO2[g][k3 + 1];
        float t0 = fmaf(n3rx, q0.x, q0.w); t0 = fmaf(n3ry, q0.y, t0); t0 = fmaf(n3rz, q0.z, t0);
        float t1 = fmaf(n3rx, q1.x, q1.w); t1 = fmaf(n3ry, q1.y, t1); t1 = fmaf(n3rz, q1.z, t1);
        m3R = f_min3(m3R, t0, t1);
        float u0 = fmaf(n3gx, q0.x, q0.w); u0 = fmaf(n3gy, q0.y, u0); u0 = fmaf(n3gz, q0.z, u0);
        float u1 = fmaf(n3gx, q1.x, q1.w); u1 = fmaf(n3gy, q1.y, u1); u1 = fmaf(n3gz, q1.z, u1);
        m3G = f_min3(m3G, u0, u1);
      }
      {
        float4 q0 = sO2[g][HCS - 1];
        float t0 = fmaf(n3rx, q0.x, q0.w); t0 = fmaf(n3ry, q0.y, t0); t0 = fmaf(n3rz, q0.z, t0);
        m3R = fminf(m3R, t0);
        float u0 = fmaf(n3gx, q0.x, q0.w); u0 = fmaf(n3gy, q0.y, u0); u0 = fmaf(n3gz, q0.z, u0);
        m3G = fminf(m3G, u0);
      }
      if (v3) {
        const size_t idx = (size_t)chunk * NHT + (size_t)b * NH + j3;
        minHR[idx] = m3R;
        minHG[idx] = m3G;
      }
    }
  }
}

// ======================= dispatch 2: mega2 =======================
template<int JS, int HCn>
__global__ __launch_bounds__(256) void mega2t(
    const float* __restrict__ recon, const float* __restrict__ gt,
    const float* __restrict__ rnorm, const float* __restrict__ gnorm,
    const float* __restrict__ obj,
    const float* __restrict__ mean, const float* __restrict__ logv,
    const float* __restrict__ vw,
    const float* __restrict__ keyR, const float* __restrict__ keyG,
    const float* __restrict__ priorK,
    const float* __restrict__ minHR, const float* __restrict__ minHG,
    float* __restrict__ accs, float* __restrict__ out)
{
  __shared__ float red[4][5];
  const int bid = blockIdx.x;
  const int tid = threadIdx.x;
  const int lane = tid & 63, wv = tid >> 6;

  if (bid < FIN_OBJ_BLKS) {
    const int b = bid / T2;
    const int tile = bid % T2;
    const int o = tile * 256 + tid;
    float penetr = 0.f, nptsv = 0.f, contactv = 0.f, consistv = 0.f, lossov = 0.f;
    if (o < NO) {
      const float* op = obj + ((size_t)b * NO + o) * 3;
      const float ox = op[0], oy = op[1], oz = op[2];
      const float o2 = ox*ox + oy*oy + oz*oz;
      const size_t base = (size_t)b * NO + o;

      float kR = 3.4e38f, kG = 3.4e38f, bP = 3.4e38f;
      #pragma unroll
      for (int s = 0; s < JS; ++s) {
        kR = fminf(kR, keyR[(size_t)s * NKEY + base]);
        kG = fminf(kG, keyG[(size_t)s * NKEY + base]);
        bP = fminf(bP, priorK[(size_t)s * NKEY + base]);
      }
      uint32 kRb = __float_as_uint(kR), kGb = __float_as_uint(kG);
      int idxR = (int)(kRb & 0x3FFu), idxG = (int)(kGb & 0x3FFu);
      float d2R = fmaxf(__uint_as_float(kRb & 0xFFFFFC00u) + o2, 0.f);
      float d2G = fmaxf(__uint_as_float(kGb & 0xFFFFFC00u) + o2, 0.f);
      float d2P = fmaxf(bP + o2, 0.f);

      const float* hR = recon + ((size_t)b * NH + idxR) * 3;
      const float* nR = rnorm + ((size_t)b * NH + idxR) * 3;
      float dotR = (ox - hR[0]) * nR[0] + (oy - hR[1]) * nR[1] + (oz - hR[2]) * nR[2];
      const float* hG = gt + ((size_t)b * NH + idxG) * 3;
      const float* nG = gnorm + ((size_t)b * NH + idxG) * 3;
      float dotG = (ox - hG[0]) * nG[0] + (oy - hG[1]) * nG[1] + (oz - hG[2]) * nG[2];

      float sgnR = (dotR > 0.f) ? 1.f : ((dotR < 0.f) ? -1.f : 0.f);
      float sgnG = (dotG > 0.f) ? 1.f : ((dotG < 0.f) ? -1.f : 0.f);
      float sR_ = sqrtf(d2R), sG_ = sqrtf(d2G);
      float o2h = sR_ * sgnR, o2hg = sG_ * sgnG;

      bool interior = dotR < 0.f;
      bool cmap = sG_ < 0.005f;
      bool rcmap = sR_ < 0.005f;

      penetr   = interior ? d2R : 0.f;
      nptsv    = cmap ? 1.f : 0.f;
      contactv = cmap ? d2P : 0.f;
      consistv = (cmap && rcmap) ? 1.f : 0.f;
      float w = (o2h < 0.f) ? 1.5f
              : (((o2hg < 0.01f) && (o2hg > -0.005f)) ? 1.f : 0.1f);
      lossov = fabsf(o2h - o2hg) * w;
    }

    float vals[5] = {penetr, nptsv, contactv, consistv, lossov};
    #pragma unroll
    for (int q = 0; q < 5; ++q) {
      float s = wave_sum(vals[q]);
      if (lane == 0) red[wv][q] = s;
    }
    __syncthreads();
    if (tid < 5) {
      float s = red[0][tid] + red[1][tid] + red[2][tid] + red[3][tid];
      atomicAdd(&accs[tid * ACC_STRIDE], s);
    }
  } else {
    const int t = (bid - FIN_OBJ_BLKS) * 256 + tid;
    float lossh = 0.f, rsum = 0.f, ksum = 0.f;
    if (t < NB * NH) {
      const float* rp = recon + (size_t)t * 3;
      const float* gp = gt + (size_t)t * 3;
      float rx = rp[0], ry = rp[1], rz = rp[2];
      float gx = gp[0], gy = gp[1], gz = gp[2];
      float d0 = rx - gx, d1 = ry - gy, d2 = rz - gz;
      rsum = d0*d0 + d1*d1 + d2*d2;

      float mRt = 3.4e38f, mGt = 3.4e38f;
      #pragma unroll
      for (int c = 0; c < HCn; ++c) {
        mRt = fminf(mRt, minHR[(size_t)c * NHT + t]);
        mGt = fminf(mGt, minHG[(size_t)c * NHT + t]);
      }
      float r2 = rx*rx + ry*ry + rz*rz;
      float g2 = gx*gx + gy*gy + gz*gz;
      float d2Rh = fmaxf(mRt + r2, 0.f);
      float d2Gh = fmaxf(mGt + g2, 0.f);
      int j = t % NH;
      lossh = fabsf(sqrtf(d2Rh) - sqrtf(d2Gh)) * powf(vw[j], 0.4f);
    }
    if (t < NB * NZ) {
      float m = mean[t], lv = logv[t];
      ksum = 1.f + lv - m * m - expf(lv);
    }
    float vals[3] = {lossh, rsum, ksum};
    #pragma unroll
    for (int q = 0; q < 3; ++q) {
      float s = wave_sum(vals[q]);
      if (lane == 0) red[wv][q] = s;
    }
    __syncthreads();
    if (tid < 3) {
      float s = red[0][tid] + red[1][tid] + red[2][tid] + red[3][tid];
      atomicAdd(&accs[(5 + tid) * ACC_STRIDE], s);
    }
  }

  // ---- fused final: last block combines ----
  __syncthreads();
  if (tid == 0) {
    __threadfence();
    int* cnt = (int*)(accs + 8 * ACC_STRIDE);
    int old = atomicAdd(cnt, 1);
    if (old == FIN_BLKS - 1) {
      float a[8];
      #pragma unroll
      for (int q = 0; q < 8; ++q) a[q] = atomicAdd(&accs[q * ACC_STRIDE], 0.0f);
      const float recon_loss = a[6] / (float)NB;
      const float kld = -0.5f * a[7] / (float)NB * 10.f;
      const float penetr = 100.f * a[0] / (float)NB;
      const float npts = a[1];
      const float contact = (npts > 0.f) ? (3000.f * a[2] / ((float)NB * npts)) : 0.f;
      const float consistency = -5.f * a[3] / (npts + 0.0001f);
      const float lossh = 35.f * (1.f - 0.005f) * (a[5] / (float)(NB * NH));
      const float losso = 30.f * (1.f - 0.005f) * (a[4] / (float)(NB * NO));
      out[0] = recon_loss + 0.1f * kld + 1000.f * penetr + 10.f * contact
             + 10.f * consistency + lossh + losso;
    }
  }
}

// =========================== PATH C (tiny ws fallback) ===========================
__global__ __launch_bounds__(256) void obj_mono(
    const float* __restrict__ recon, const float* __restrict__ gt,
    const float* __restrict__ rnorm, const float* __restrict__ gnorm,
    const float* __restrict__ obj, float* __restrict__ accs)
{
  __shared__ float4 sR[NH];
  __shared__ float4 sG[NH];
  __shared__ float red[4][5];
  const int b = blockIdx.x / 12;
  const int tile = blockIdx.x % 12;
  const int tid = threadIdx.x;
  for (int i = tid; i < NH; i += 256) {
    const float* p = recon + ((size_t)b * NH + i) * 3;
    float x = p[0], y = p[1], z = p[2];
    sR[i] = make_float4(x, y, z, x*x + y*y + z*z);
    const float* q = gt + ((size_t)b * NH + i) * 3;
    float gx = q[0], gy = q[1], gz = q[2];
    sG[i] = make_float4(gx, gy, gz, gx*gx + gy*gy + gz*gz);
  }
  __syncthreads();
  const int o = tile * 256 + tid;
  float penetr = 0.f, nptsv = 0.f, contactv = 0.f, consistv = 0.f, lossov = 0.f;
  if (o < NO) {
    const float* op = obj + ((size_t)b * NO + o) * 3;
    const float ox = op[0], oy = op[1], oz = op[2];
    const float nx = -2.f*ox, ny = -2.f*oy, nz = -2.f*oz;
    const float o2 = ox*ox + oy*oy + oz*oz;
    float bR = 3.4e38f, bG = 3.4e38f; int iR = 0, iG = 0;
    for (int i = 0; i < NH; ++i) {
      float4 h = sR[i];
      float t = fmaf(nx, h.x, h.w); t = fmaf(ny, h.y, t); t = fmaf(nz, h.z, t);
      if (t < bR) { bR = t; iR = i; }
      float4 g = sG[i];
      float u = fmaf(nx, g.x, g.w); u = fmaf(ny, g.y, u); u = fmaf(nz, g.z, u);
      if (u < bG) { bG = u; iG = i; }
    }
    float bP = 3.4e38f;
    for (int k = 0; k < NP; ++k) {
      float4 h = sR[c_prior[k]];
      float t = fmaf(nx, h.x, h.w); t = fmaf(ny, h.y, t); t = fmaf(nz, h.z, t);
      bP = fminf(bP, t);
    }
    float d2R = fmaxf(bR + o2, 0.f);
    float d2G = fmaxf(bG + o2, 0.f);
    float d2P = fmaxf(bP + o2, 0.f);
    float4 hR = sR[iR];
    const float* nR = rnorm + ((size_t)b * NH + iR) * 3;
    float dotR = (ox-hR.x)*nR[0] + (oy-hR.y)*nR[1] + (oz-hR.z)*nR[2];
    float4 hG = sG[iG];
    const float* nG = gnorm + ((size_t)b * NH + iG) * 3;
    float dotG = (ox-hG.x)*nG[0] + (oy-hG.y)*nG[1] + (oz-hG.z)*nG[2];
    float sgnR = (dotR > 0.f) ? 1.f : ((dotR < 0.f) ? -1.f : 0.f);
    float sgnG = (dotG > 0.f) ? 1.f : ((dotG < 0.f) ? -1.f : 0.f);
    float sR_ = sqrtf(d2R), sG_ = sqrtf(d2G);
    float o2h = sR_*sgnR, o2hg = sG_*sgnG;
    bool interior = dotR < 0.f;
    bool cmap = sG_ < 0.005f, rcmap = sR_ < 0.005f;
    penetr = interior ? d2R : 0.f;
    nptsv = cmap ? 1.f : 0.f;
    contactv = cmap ? d2P : 0.f;
    consistv = (cmap && rcmap) ? 1.f : 0.f;
    float w = (o2h < 0.f) ? 1.5f : (((o2hg < 0.01f) && (o2hg > -0.005f)) ? 1.f : 0.1f);
    lossov = fabsf(o2h - o2hg) * w;
  }
  float vals[5] = {penetr, nptsv, contactv, consistv, lossov};
  const int lane = tid & 63, wv = tid >> 6;
  for (int q = 0; q < 5; ++q) {
    float s = wave_sum(vals[q]);
    if (lane == 0) red[wv][q] = s;
  }
  __syncthreads();
  if (tid < 5) {
    float s = red[0][tid] + red[1][tid] + red[2][tid] + red[3][tid];
    atomicAdd(&accs[tid * ACC_STRIDE], s);
  }
}

__global__ __launch_bounds__(256) void hand_full(
    const float* __restrict__ recon, const float* __restrict__ gt,
    const float* __restrict__ obj, const float* __restrict__ vw,
    float* __restrict__ accs)
{
  __shared__ float4 sO[500];
  __shared__ float red[4];
  const int b = blockIdx.x >> 2;
  const int j = ((blockIdx.x & 3) << 8) + threadIdx.x;
  const bool valid = j < NH;
  float rx=0,ry=0,rz=0,gx=0,gy=0,gz=0;
  if (valid) {
    const float* rp = recon + ((size_t)b * NH + j) * 3;
    const float* gp = gt + ((size_t)b * NH + j) * 3;
    rx=rp[0];ry=rp[1];rz=rp[2]; gx=gp[0];gy=gp[1];gz=gp[2];
  }
  const float nrx=-2.f*rx, nry=-2.f*ry, nrz=-2.f*rz;
  const float ngx=-2.f*gx, ngy=-2.f*gy, ngz=-2.f*gz;
  const float r2 = rx*rx+ry*ry+rz*rz, g2 = gx*gx+gy*gy+gz*gz;
  float mR = 3.4e38f, mG = 3.4e38f;
  for (int oc = 0; oc < 6; ++oc) {
    __syncthreads();
    const float* Ob = obj + ((size_t)b * NO + oc * 500) * 3;
    for (int i = threadIdx.x; i < 500; i += 256) {
      float x = Ob[3*i], y = Ob[3*i+1], z = Ob[3*i+2];
      sO[i] = make_float4(x, y, z, x*x + y*y + z*z);
    }
    __syncthreads();
    if (valid) {
      for (int k = 0; k < 500; ++k) {
        float4 o4 = sO[k];
        float t = fmaf(nrx,o4.x,o4.w); t = fmaf(nry,o4.y,t); t = fmaf(nrz,o4.z,t);
        mR = fminf(mR, t);
        float u = fmaf(ngx,o4.x,o4.w); u = fmaf(ngy,o4.y,u); u = fmaf(ngz,o4.z,u);
        mG = fminf(mG, u);
      }
    }
  }
  float lossh = valid ? fabsf(sqrtf(fmaxf(mR+r2,0.f)) - sqrtf(fmaxf(mG+g2,0.f))) * powf(vw[j], 0.4f) : 0.f;
  const int lane = threadIdx.x & 63, wv = threadIdx.x >> 6;
  float s = wave_sum(lossh);
  if (lane == 0) red[wv] = s;
  __syncthreads();
  if (threadIdx.x == 0) atomicAdd(&accs[5 * ACC_STRIDE], red[0]+red[1]+red[2]+red[3]);
}

__global__ __launch_bounds__(256) void tail_nomins(
    const float* __restrict__ recon, const float* __restrict__ gt,
    const float* __restrict__ mean, const float* __restrict__ logv,
    float* __restrict__ accs)
{
  __shared__ float red[4][2];
  const int t = blockIdx.x * 256 + threadIdx.x;
  float rsum = 0.f, ksum = 0.f;
  if (t < NB * NH) {
    const float* rp = recon + (size_t)t * 3;
    const float* gp = gt + (size_t)t * 3;
    float d0 = rp[0]-gp[0], d1 = rp[1]-gp[1], d2 = rp[2]-gp[2];
    rsum = d0*d0 + d1*d1 + d2*d2;
  }
  if (t < NB * NZ) {
    float m = mean[t], lv = logv[t];
    ksum = 1.f + lv - m*m - expf(lv);
  }
  float vals[2] = {rsum, ksum};
  const int lane = threadIdx.x & 63, wv = threadIdx.x >> 6;
  for (int q = 0; q < 2; ++q) {
    float s = wave_sum(vals[q]);
    if (lane == 0) red[wv][q] = s;
  }
  __syncthreads();
  if (threadIdx.x < 2) {
    float s = red[0][threadIdx.x] + red[1][threadIdx.x] + red[2][threadIdx.x] + red[3][threadIdx.x];
    atomicAdd(&accs[(6 + threadIdx.x) * ACC_STRIDE], s);
  }
}

__global__ void init_small(float* accs) {
  int t = threadIdx.x;
  accs[t] = 0.0f;
  accs[t + 256] = 0.0f;
}

__global__ void final_fb(const float* __restrict__ a, float* __restrict__ out) {
  const float recon_loss = a[6 * ACC_STRIDE] / (float)NB;
  const float kld = -0.5f * a[7 * ACC_STRIDE] / (float)NB * 10.f;
  const float penetr = 100.f * a[0] / (float)NB;
  const float npts = a[1 * ACC_STRIDE];
  const float contact = (npts > 0.f) ? (3000.f * a[2 * ACC_STRIDE] / ((float)NB * npts)) : 0.f;
  const float consistency = -5.f * a[3 * ACC_STRIDE] / (npts + 0.0001f);
  const float lossh = 35.f * (1.f - 0.005f) * (a[5 * ACC_STRIDE] / (float)(NB * NH));
  const float losso = 30.f * (1.f - 0.005f) * (a[4 * ACC_STRIDE] / (float)(NB * NO));
  out[0] = recon_loss + 0.1f*kld + 1000.f*penetr + 10.f*contact + 10.f*consistency + lossh + losso;
}

extern "C" void kernel_launch(void* const* d_in, const int* in_sizes, int n_in,
                              void* d_out, int out_size, void* d_ws, size_t ws_size,
                              hipStream_t stream) {
  const float* recon = (const float*)d_in[0];
  const float* gt    = (const float*)d_in[1];
  const float* rnorm = (const float*)d_in[2];
  const float* gnorm = (const float*)d_in[3];
  const float* obj   = (const float*)d_in[4];
  const float* mean  = (const float*)d_in[5];
  const float* logv  = (const float*)d_in[6];
  const float* vw    = (const float*)d_in[7];
  float* out = (float*)d_out;

  // ws: padded accs[512] @0 (2048B) | keyR[8N] keyG[8N] priorK[8N]
  //     minHR[24H] minHG[24H]
  float* accs = (float*)d_ws;
  float* base = (float*)((char*)d_ws + ACC_FLOATS * sizeof(float));

  const size_t needed = ACC_FLOATS * sizeof(float)
                      + (3ull * JS8 * NKEY + 2ull * HC24 * NHT) * sizeof(float);

  if (ws_size >= needed) {
    float* keyR   = base;
    float* keyG   = keyR + (size_t)JS8 * NKEY;
    float* priorK = keyG + (size_t)JS8 * NKEY;
    float* minHR  = priorK + (size_t)JS8 * NKEY;
    float* minHG  = minHR + (size_t)HC24 * NHT;
    mega1f<<<OBJ_B + HAND_B, 256, 0, stream>>>(
        recon, gt, obj, keyR, keyG, priorK, minHR, minHG, accs);
    mega2t<JS8, HC24><<<FIN_BLKS, 256, 0, stream>>>(
        recon, gt, rnorm, gnorm, obj, mean, logv, vw,
        keyR, keyG, priorK, minHR, minHG, accs, out);
  } else {
    init_small<<<1, 256, 0, stream>>>(accs);
    obj_mono<<<NB * 12, 256, 0, stream>>>(recon, gt, rnorm, gnorm, obj, accs);
    hand_full<<<NB * 4, 256, 0, stream>>>(recon, gt, obj, vw, accs);
    tail_nomins<<<(NB * NH + 255) / 256, 256, 0, stream>>>(recon, gt, mean, logv, accs);
    final_fb<<<1, 1, 0, stream>>>(accs, out);
  }
}

// Round 6
// 115.592 us; speedup vs baseline: 1.2291x; 1.0544x over previous
//
#include <hip/hip_runtime.h>
#include <math.h>

// GraspCVAE loss, MI355X — round 14.
// R13 post-mortem: ds_read -40% at same FMA count = NEUTRAL -> LDS-read
// theory dead (joins VALU-count R9, occupancy R10). mega1 reverted to R11
// exact (best total 118.8).
// Remaining un-falsified cost: mega2's last-block-combine protocol. EVERY
// one of 482 blocks runs __threadfence() (device-scope release = L2
// writeback on non-coherent-XCD gfx950) + an atomic RMW on one counter
// line. Prior session measured this exact pattern at 60-100us for 768
// blocks ("kernel boundary is cheaper"); scaled 482/768 -> ~38-63us, which
// matches the unexplained budget (118.8 - 42 mega1 - ~15 mega2-work).
// R14: strip fence+counter+readback from mega2 (blocks atomicAdd and EXIT);
// combine moves to a 1-block final_fb dispatch (~3us launch).
// Predict: total 118.8 -> ~90-105 if fence theory right; +-4 = dead theory.

#define NB 32
#define NH 778
#define NO 3000
#define NZ 64
#define NP 204

#define P_OBJ 4
#define OBJ_PTS 1024
#define OBJ_TILES 3                   // ceil(3000/1024)
#define JS8 8
#define JC8 98                        // ceil(778/8)
#define HC24 24
#define HCS 125                       // 3000/24

#define T2 12                         // mega2 obj tiles (256 pts)
#define FIN_OBJ_BLKS (NB * T2)                // 384
#define FIN_TAIL_BLKS ((NB * NH + 255) / 256) // 98
#define FIN_BLKS (FIN_OBJ_BLKS + FIN_TAIL_BLKS) // 482

#define NKEY (NB * NO)                // 96000
#define NHT  (NB * NH)                // 24896

// accumulator padding: each logical slot q lives at accs[q*ACC_STRIDE]
#define ACC_STRIDE 32                 // 32 floats = 128 B = own cache line
#define ACC_FLOATS 512                // 16 slots * 32

typedef unsigned int uint32;

// original order (used by PATH C)
__device__ __constant__ int c_prior[NP] = {
  697,698,699,700,712,713,714,715,737,738,739,740,741,743,744,745,746,748,749,750,
  753,754,755,756,757,758,759,760,761,762,763,764,765,766,767,768,
  46,47,48,49,164,165,166,167,194,195,223,237,238,280,281,298,301,317,320,323,
  324,325,326,327,328,329,330,331,332,333,340,341,342,343,344,345,346,347,348,349,
  350,351,352,353,354,355,
  356,357,358,359,375,376,386,387,396,397,402,403,413,429,433,434,435,436,437,438,
  439,440,441,442,443,444,452,453,454,455,456,459,460,461,462,463,464,465,466,467,
  468,469,470,471,484,485,486,496,497,506,507,513,514,524,545,546,547,548,549,550,
  551,552,553,555,563,564,565,566,567,570,572,573,574,575,576,577,578,
  580,581,582,583,600,601,602,614,615,624,625,630,631,641,663,664,665,666,667,668,
  670,672,680,681,682,683,684,686,687,688,689,690,691,692,693,694,695,
  73,96,98,99,772,774,775,777
};

// globally ascending sorted prior list
__device__ __constant__ int c_prior_sorted[NP] = {
  46,47,48,49,73,96,98,99,164,165,166,167,194,
  195,223,237,238,280,281,298,301,317,320,323,324,325,326,327,328,329,330,331,
  332,333,340,341,342,343,344,345,346,347,348,349,350,351,352,353,354,355,356,
  357,358,359,375,376,386,387,
  396,397,402,403,413,429,433,434,435,436,437,438,439,440,441,442,443,444,452,
  453,454,455,456,459,460,461,462,463,464,465,466,467,468,469,470,471,484,485,
  486,496,497,506,507,513,514,524,545,546,547,548,549,550,551,552,553,555,563,
  564,565,566,567,570,572,573,574,575,576,577,578,580,581,582,583,
  600,601,602,614,615,624,625,630,631,641,663,664,665,666,667,668,670,672,680,
  681,682,683,684,686,687,688,689,690,691,692,693,694,695,697,698,699,700,712,
  713,714,715,737,738,739,740,741,743,744,745,746,748,749,750,753,754,755,756,
  757,758,759,760,761,762,763,764,765,766,767,768,772,774,775,777
};
// position ranges in c_prior_sorted for j in [s*98, (s+1)*98)
__device__ __constant__ int c_psplit8[9] = {0, 6, 14, 19, 58, 97, 131, 154, 204};

__device__ inline float wave_sum(float v) {
  v += __shfl_down(v, 32);
  v += __shfl_down(v, 16);
  v += __shfl_down(v, 8);
  v += __shfl_down(v, 4);
  v += __shfl_down(v, 2);
  v += __shfl_down(v, 1);
  return v;
}

// forced 3-operand VALU ops (R9: verified correct)
__device__ __forceinline__ float f_min3(float a, float b, float c) {
  float r;
  asm("v_min3_f32 %0, %1, %2, %3" : "=v"(r) : "v"(a), "v"(b), "v"(c));
  return r;
}
__device__ __forceinline__ float f_packao(float t, int j, uint32 mask) {
  float r;
  asm("v_and_or_b32 %0, %1, %2, %3" : "=v"(r) : "v"(t), "s"(mask), "v"(j));
  return r;
}

// ======================= dispatch 1: mega1 (R11-exact) =======================
// accs logical slots (each at q*ACC_STRIDE): 0 penetr, 1 npts, 2 contact,
// 3 consist, 4 loss_o, 5 loss_h, 6 recon_sq, 7 kld
__global__ __launch_bounds__(256) void mega1t(
    const float* __restrict__ recon, const float* __restrict__ gt,
    const float* __restrict__ obj,
    float* __restrict__ keyR, float* __restrict__ keyG,
    float* __restrict__ priorK,
    float* __restrict__ minHR, float* __restrict__ minHG,
    float* __restrict__ accs)
{
  const int OBJ_B = NB * OBJ_TILES * JS8;   // 768
  const int bid = blockIdx.x;
  const int tid = threadIdx.x;
  const uint32 KMASK = 0xFFFFFC00u;

  if (bid == 0) {  // zero padded accumulator region (consumed after boundary)
    accs[tid] = 0.0f;
    accs[tid + 256] = 0.0f;
  }

  if (bid < OBJ_B) {
    // ---- obj -> hand NN (j-split 8) + in-pass partial prior-NN ----
    __shared__ float4 shA[JC8];   // recon split
    __shared__ float4 shB[JC8];   // gt split
    const int b     = bid / (OBJ_TILES * JS8);
    const int rem   = bid % (OBJ_TILES * JS8);
    const int tile  = rem / JS8;
    const int split = rem % JS8;
    const int jbase = split * JC8;
    const int jcnt  = (NH - jbase < JC8) ? (NH - jbase) : JC8;

    for (int i = tid; i < jcnt; i += 256) {
      const float* p = recon + ((size_t)b * NH + jbase + i) * 3;
      float x = p[0], y = p[1], z = p[2];
      shA[i] = make_float4(x, y, z, x*x + y*y + z*z);
      const float* q = gt + ((size_t)b * NH + jbase + i) * 3;
      float gx = q[0], gy = q[1], gz = q[2];
      shB[i] = make_float4(gx, gy, gz, gx*gx + gy*gy + gz*gz);
    }
    __syncthreads();

    float nx[P_OBJ], ny[P_OBJ], nz[P_OBJ];
    int ob[P_OBJ]; bool val[P_OBJ];
    #pragma unroll
    for (int m = 0; m < P_OBJ; ++m) {
      int o = tile * OBJ_PTS + m * 256 + tid;
      ob[m] = o; val[m] = (o < NO);
      float x = 0.f, y = 0.f, z = 0.f;
      if (val[m]) {
        const float* op = obj + ((size_t)b * NO + o) * 3;
        x = op[0]; y = op[1]; z = op[2];
      }
      nx[m] = -2.f * x; ny[m] = -2.f * y; nz[m] = -2.f * z;
    }

    float bR[P_OBJ], bG[P_OBJ];
    #pragma unroll
    for (int m = 0; m < P_OBJ; ++m) { bR[m] = 3.4e38f; bG[m] = 3.4e38f; }

#define RSTEP(hh0, hh1, jj0, jj1) \
    { _Pragma("unroll") for (int m = 0; m < P_OBJ; ++m) { \
        float t0 = fmaf(nx[m], hh0.x, hh0.w); t0 = fmaf(ny[m], hh0.y, t0); t0 = fmaf(nz[m], hh0.z, t0); \
        float t1 = fmaf(nx[m], hh1.x, hh1.w); t1 = fmaf(ny[m], hh1.y, t1); t1 = fmaf(nz[m], hh1.z, t1); \
        bR[m] = f_min3(bR[m], f_packao(t0, jj0, KMASK), f_packao(t1, jj1, KMASK)); } }
#define GSTEP(gg0, gg1, jj0, jj1) \
    { _Pragma("unroll") for (int m = 0; m < P_OBJ; ++m) { \
        float u0 = fmaf(nx[m], gg0.x, gg0.w); u0 = fmaf(ny[m], gg0.y, u0); u0 = fmaf(nz[m], gg0.z, u0); \
        float u1 = fmaf(nx[m], gg1.x, gg1.w); u1 = fmaf(ny[m], gg1.y, u1); u1 = fmaf(nz[m], gg1.z, u1); \
        bG[m] = f_min3(bG[m], f_packao(u0, jj0, KMASK), f_packao(u1, jj1, KMASK)); } }

    // interleaved prefetch: every LDS read pair is covered by a VALU phase
    float4 h0 = shA[0], h1 = shA[1];
    int i = 0;
    for (; i + 3 < jcnt; i += 2) {
      float4 g0 = shB[i], g1 = shB[i + 1];
      RSTEP(h0, h1, jbase + i, jbase + i + 1);
      float4 hn0 = shA[i + 2], hn1 = shA[i + 3];
      GSTEP(g0, g1, jbase + i, jbase + i + 1);
      h0 = hn0; h1 = hn1;
    }
    {
      float4 g0 = shB[i], g1 = shB[i + 1];
      RSTEP(h0, h1, jbase + i, jbase + i + 1);
      GSTEP(g0, g1, jbase + i, jbase + i + 1);
      i += 2;
    }
    for (; i < jcnt; ++i) {
      float4 hh = shA[i], gg = shB[i];
      #pragma unroll
      for (int m = 0; m < P_OBJ; ++m) {
        float t0 = fmaf(nx[m], hh.x, hh.w); t0 = fmaf(ny[m], hh.y, t0); t0 = fmaf(nz[m], hh.z, t0);
        bR[m] = fminf(bR[m], f_packao(t0, jbase + i, KMASK));
        float u0 = fmaf(nx[m], gg.x, gg.w); u0 = fmaf(ny[m], gg.y, u0); u0 = fmaf(nz[m], gg.z, u0);
        bG[m] = fminf(bG[m], f_packao(u0, jbase + i, KMASK));
      }
    }
#undef RSTEP
#undef GSTEP

    // partial prior-NN over this split's prior members (candidates in shA)
    float bP[P_OBJ];
    #pragma unroll
    for (int m = 0; m < P_OBJ; ++m) bP[m] = 3.4e38f;
    const int pk0 = c_psplit8[split], pk1 = c_psplit8[split + 1];
    int k = pk0;
    for (; k + 1 < pk1; k += 2) {
      float4 ha = shA[c_prior_sorted[k] - jbase];
      float4 hb = shA[c_prior_sorted[k + 1] - jbase];
      #pragma unroll
      for (int m = 0; m < P_OBJ; ++m) {
        float t = fmaf(nx[m], ha.x, ha.w); t = fmaf(ny[m], ha.y, t); t = fmaf(nz[m], ha.z, t);
        float u = fmaf(nx[m], hb.x, hb.w); u = fmaf(ny[m], hb.y, u); u = fmaf(nz[m], hb.z, u);
        bP[m] = f_min3(bP[m], t, u);
      }
    }
    if (k < pk1) {
      float4 ha = shA[c_prior_sorted[k] - jbase];
      #pragma unroll
      for (int m = 0; m < P_OBJ; ++m) {
        float t = fmaf(nx[m], ha.x, ha.w); t = fmaf(ny[m], ha.y, t); t = fmaf(nz[m], ha.z, t);
        bP[m] = fminf(bP[m], t);
      }
    }

    #pragma unroll
    for (int m = 0; m < P_OBJ; ++m) {
      if (!val[m]) continue;
      const size_t idx = (size_t)split * NKEY + (size_t)b * NO + ob[m];
      keyR[idx] = bR[m];
      keyG[idx] = bG[m];
      priorK[idx] = bP[m];
    }
  } else {
    // ---- hand -> obj NN, 24 chunks; prefetched k-loop + rotating tail ----
    __shared__ float4 sO[HCS];
    const int bid2 = bid - OBJ_B;
    const int oc = bid2 % HC24;
    const int b  = bid2 / HC24;

    const float* Ob = obj + ((size_t)b * NO + oc * HCS) * 3;
    for (int i2 = tid; i2 < HCS; i2 += 256) {
      float x = Ob[3*i2], y = Ob[3*i2+1], z = Ob[3*i2+2];
      sO[i2] = make_float4(x, y, z, x*x + y*y + z*z);
    }
    __syncthreads();

    float nrx[3], nry[3], nrz[3];
    float ngx[3], ngy[3], ngz[3];
    #pragma unroll
    for (int m = 0; m < 3; ++m) {
      const int j = m * 256 + tid;                 // 0..767, always valid
      const float* rp = recon + ((size_t)b * NH + j) * 3;
      const float* gp = gt    + ((size_t)b * NH + j) * 3;
      nrx[m] = -2.f*rp[0]; nry[m] = -2.f*rp[1]; nrz[m] = -2.f*rp[2];
      ngx[m] = -2.f*gp[0]; ngy[m] = -2.f*gp[1]; ngz[m] = -2.f*gp[2];
    }

    float mR[3], mG[3];
    #pragma unroll
    for (int m = 0; m < 3; ++m) { mR[m] = 3.4e38f; mG[m] = 3.4e38f; }

#define HSTEP(oo0, oo1) \
    { _Pragma("unroll") for (int m = 0; m < 3; ++m) { \
        float t0 = fmaf(nrx[m], oo0.x, oo0.w); t0 = fmaf(nry[m], oo0.y, t0); t0 = fmaf(nrz[m], oo0.z, t0); \
        float t1 = fmaf(nrx[m], oo1.x, oo1.w); t1 = fmaf(nry[m], oo1.y, t1); t1 = fmaf(nrz[m], oo1.z, t1); \
        mR[m] = f_min3(mR[m], t0, t1); \
        float u0 = fmaf(ngx[m], oo0.x, oo0.w); u0 = fmaf(ngy[m], oo0.y, u0); u0 = fmaf(ngz[m], oo0.z, u0); \
        float u1 = fmaf(ngx[m], oo1.x, oo1.w); u1 = fmaf(ngy[m], oo1.y, u1); u1 = fmaf(ngz[m], oo1.z, u1); \
        mG[m] = f_min3(mG[m], u0, u1); } }

    float4 o0 = sO[0], o1 = sO[1];
    int k2 = 0;
    for (; k2 + 3 < HCS; k2 += 2) {
      float4 a0 = sO[k2 + 2], a1 = sO[k2 + 3];
      HSTEP(o0, o1);
      o0 = a0; o1 = a1;
    }
    HSTEP(o0, o1);
    k2 += 2;
    for (; k2 < HCS; ++k2) {                      // HCS=125 odd: 1 leftover
      float4 oc4 = sO[k2];
      #pragma unroll
      for (int m = 0; m < 3; ++m) {
        float t0 = fmaf(nrx[m], oc4.x, oc4.w); t0 = fmaf(nry[m], oc4.y, t0); t0 = fmaf(nrz[m], oc4.z, t0);
        mR[m] = fminf(mR[m], t0);
        float u0 = fmaf(ngx[m], oc4.x, oc4.w); u0 = fmaf(ngy[m], oc4.y, u0); u0 = fmaf(ngz[m], oc4.z, u0);
        mG[m] = fminf(mG[m], u0);
      }
    }
#undef HSTEP

    #pragma unroll
    for (int m = 0; m < 3; ++m) {
      const int j = m * 256 + tid;
      const size_t idx = (size_t)oc * NHT + (size_t)b * NH + j;
      minHR[idx] = mR[m];
      minHG[idx] = mG[m];
    }

    // tail: hand points 768..777 on one wave, rotated per block
    const int tw = bid2 & 3;
    if ((tid >> 6) == tw) {
      const int j3 = 768 + (tid & 63);
      const bool v3 = (j3 < NH);                   // lanes 0..9
      float rx=0.f,ry=0.f,rz=0.f,gx=0.f,gy=0.f,gz=0.f;
      if (v3) {
        const float* rp = recon + ((size_t)b * NH + j3) * 3;
        const float* gp = gt    + ((size_t)b * NH + j3) * 3;
        rx=rp[0];ry=rp[1];rz=rp[2]; gx=gp[0];gy=gp[1];gz=gp[2];
      }
      const float n3rx=-2.f*rx, n3ry=-2.f*ry, n3rz=-2.f*rz;
      const float n3gx=-2.f*gx, n3gy=-2.f*gy, n3gz=-2.f*gz;
      float m3R = 3.4e38f, m3G = 3.4e38f;
      int k3 = 0;
      for (; k3 + 1 < HCS; k3 += 2) {
        float4 q0 = sO[k3], q1 = sO[k3 + 1];
        float t0 = fmaf(n3rx, q0.x, q0.w); t0 = fmaf(n3ry, q0.y, t0); t0 = fmaf(n3rz, q0.z, t0);
        float t1 = fmaf(n3rx, q1.x, q1.w); t1 = fmaf(n3ry, q1.y, t1); t1 = fmaf(n3rz, q1.z, t1);
        m3R = f_min3(m3R, t0, t1);
        float u0 = fmaf(n3gx, q0.x, q0.w); u0 = fmaf(n3gy, q0.y, u0); u0 = fmaf(n3gz, q0.z, u0);
        float u1 = fmaf(n3gx, q1.x, q1.w); u1 = fmaf(n3gy, q1.y, u1); u1 = fmaf(n3gz, q1.z, u1);
        m3G = f_min3(m3G, u0, u1);
      }
      {
        float4 q0 = sO[HCS - 1];
        float t0 = fmaf(n3rx, q0.x, q0.w); t0 = fmaf(n3ry, q0.y, t0); t0 = fmaf(n3rz, q0.z, t0);
        m3R = fminf(m3R, t0);
        float u0 = fmaf(n3gx, q0.x, q0.w); u0 = fmaf(n3gy, q0.y, u0); u0 = fmaf(n3gz, q0.z, u0);
        m3G = fminf(m3G, u0);
      }
      if (v3) {
        const size_t idx = (size_t)oc * NHT + (size_t)b * NH + j3;
        minHR[idx] = m3R;
        minHG[idx] = m3G;
      }
    }
  }
}

// ======================= dispatch 2: mega2 (no fence/counter) ===============
__global__ __launch_bounds__(256) void mega2n(
    const float* __restrict__ recon, const float* __restrict__ gt,
    const float* __restrict__ rnorm, const float* __restrict__ gnorm,
    const float* __restrict__ obj,
    const float* __restrict__ mean, const float* __restrict__ logv,
    const float* __restrict__ vw,
    const float* __restrict__ keyR, const float* __restrict__ keyG,
    const float* __restrict__ priorK,
    const float* __restrict__ minHR, const float* __restrict__ minHG,
    float* __restrict__ accs)
{
  __shared__ float red[4][5];
  const int bid = blockIdx.x;
  const int tid = threadIdx.x;
  const int lane = tid & 63, wv = tid >> 6;

  if (bid < FIN_OBJ_BLKS) {
    const int b = bid / T2;
    const int tile = bid % T2;
    const int o = tile * 256 + tid;
    float penetr = 0.f, nptsv = 0.f, contactv = 0.f, consistv = 0.f, lossov = 0.f;
    if (o < NO) {
      const float* op = obj + ((size_t)b * NO + o) * 3;
      const float ox = op[0], oy = op[1], oz = op[2];
      const float o2 = ox*ox + oy*oy + oz*oz;
      const size_t base = (size_t)b * NO + o;

      float kR = 3.4e38f, kG = 3.4e38f, bP = 3.4e38f;
      #pragma unroll
      for (int s = 0; s < JS8; ++s) {
        kR = fminf(kR, keyR[(size_t)s * NKEY + base]);
        kG = fminf(kG, keyG[(size_t)s * NKEY + base]);
        bP = fminf(bP, priorK[(size_t)s * NKEY + base]);
      }
      uint32 kRb = __float_as_uint(kR), kGb = __float_as_uint(kG);
      int idxR = (int)(kRb & 0x3FFu), idxG = (int)(kGb & 0x3FFu);
      float d2R = fmaxf(__uint_as_float(kRb & 0xFFFFFC00u) + o2, 0.f);
      float d2G = fmaxf(__uint_as_float(kGb & 0xFFFFFC00u) + o2, 0.f);
      float d2P = fmaxf(bP + o2, 0.f);

      const float* hR = recon + ((size_t)b * NH + idxR) * 3;
      const float* nR = rnorm + ((size_t)b * NH + idxR) * 3;
      float dotR = (ox - hR[0]) * nR[0] + (oy - hR[1]) * nR[1] + (oz - hR[2]) * nR[2];
      const float* hG = gt + ((size_t)b * NH + idxG) * 3;
      const float* nG = gnorm + ((size_t)b * NH + idxG) * 3;
      float dotG = (ox - hG[0]) * nG[0] + (oy - hG[1]) * nG[1] + (oz - hG[2]) * nG[2];

      float sgnR = (dotR > 0.f) ? 1.f : ((dotR < 0.f) ? -1.f : 0.f);
      float sgnG = (dotG > 0.f) ? 1.f : ((dotG < 0.f) ? -1.f : 0.f);
      float sR_ = sqrtf(d2R), sG_ = sqrtf(d2G);
      float o2h = sR_ * sgnR, o2hg = sG_ * sgnG;

      bool interior = dotR < 0.f;
      bool cmap = sG_ < 0.005f;
      bool rcmap = sR_ < 0.005f;

      penetr   = interior ? d2R : 0.f;
      nptsv    = cmap ? 1.f : 0.f;
      contactv = cmap ? d2P : 0.f;
      consistv = (cmap && rcmap) ? 1.f : 0.f;
      float w = (o2h < 0.f) ? 1.5f
              : (((o2hg < 0.01f) && (o2hg > -0.005f)) ? 1.f : 0.1f);
      lossov = fabsf(o2h - o2hg) * w;
    }

    float vals[5] = {penetr, nptsv, contactv, consistv, lossov};
    #pragma unroll
    for (int q = 0; q < 5; ++q) {
      float s = wave_sum(vals[q]);
      if (lane == 0) red[wv][q] = s;
    }
    __syncthreads();
    if (tid < 5) {
      float s = red[0][tid] + red[1][tid] + red[2][tid] + red[3][tid];
      atomicAdd(&accs[tid * ACC_STRIDE], s);
    }
  } else {
    const int t = (bid - FIN_OBJ_BLKS) * 256 + tid;
    float lossh = 0.f, rsum = 0.f, ksum = 0.f;
    if (t < NB * NH) {
      const float* rp = recon + (size_t)t * 3;
      const float* gp = gt + (size_t)t * 3;
      float rx = rp[0], ry = rp[1], rz = rp[2];
      float gx = gp[0], gy = gp[1], gz = gp[2];
      float d0 = rx - gx, d1 = ry - gy, d2 = rz - gz;
      rsum = d0*d0 + d1*d1 + d2*d2;

      float mRt = 3.4e38f, mGt = 3.4e38f;
      #pragma unroll
      for (int c = 0; c < HC24; ++c) {
        mRt = fminf(mRt, minHR[(size_t)c * NHT + t]);
        mGt = fminf(mGt, minHG[(size_t)c * NHT + t]);
      }
      float r2 = rx*rx + ry*ry + rz*rz;
      float g2 = gx*gx + gy*gy + gz*gz;
      float d2Rh = fmaxf(mRt + r2, 0.f);
      float d2Gh = fmaxf(mGt + g2, 0.f);
      int j = t % NH;
      lossh = fabsf(sqrtf(d2Rh) - sqrtf(d2Gh)) * powf(vw[j], 0.4f);
    }
    if (t < NB * NZ) {
      float m = mean[t], lv = logv[t];
      ksum = 1.f + lv - m * m - expf(lv);
    }
    float vals[3] = {lossh, rsum, ksum};
    #pragma unroll
    for (int q = 0; q < 3; ++q) {
      float s = wave_sum(vals[q]);
      if (lane == 0) red[wv][q] = s;
    }
    __syncthreads();
    if (tid < 3) {
      float s = red[0][tid] + red[1][tid] + red[2][tid] + red[3][tid];
      atomicAdd(&accs[(5 + tid) * ACC_STRIDE], s);
    }
  }
  // no fence, no counter, no readback — kernel boundary orders everything
}

// ======================= dispatch 3: final combine =======================
__global__ void final_fb(const float* __restrict__ a, float* __restrict__ out) {
  const float recon_loss = a[6 * ACC_STRIDE] / (float)NB;
  const float kld = -0.5f * a[7 * ACC_STRIDE] / (float)NB * 10.f;
  const float penetr = 100.f * a[0] / (float)NB;
  const float npts = a[1 * ACC_STRIDE];
  const float contact = (npts > 0.f) ? (3000.f * a[2 * ACC_STRIDE] / ((float)NB * npts)) : 0.f;
  const float consistency = -5.f * a[3 * ACC_STRIDE] / (npts + 0.0001f);
  const float lossh = 35.f * (1.f - 0.005f) * (a[5 * ACC_STRIDE] / (float)(NB * NH));
  const float losso = 30.f * (1.f - 0.005f) * (a[4 * ACC_STRIDE] / (float)(NB * NO));
  out[0] = recon_loss + 0.1f*kld + 1000.f*penetr + 10.f*contact + 10.f*consistency + lossh + losso;
}

// =========================== PATH C (tiny ws fallback) ===========================
__global__ __launch_bounds__(256) void obj_mono(
    const float* __restrict__ recon, const float* __restrict__ gt,
    const float* __restrict__ rnorm, const float* __restrict__ gnorm,
    const float* __restrict__ obj, float* __restrict__ accs)
{
  __shared__ float4 sR[NH];
  __shared__ float4 sG[NH];
  __shared__ float red[4][5];
  const int b = blockIdx.x / 12;
  const int tile = blockIdx.x % 12;
  const int tid = threadIdx.x;
  for (int i = tid; i < NH; i += 256) {
    const float* p = recon + ((size_t)b * NH + i) * 3;
    float x = p[0], y = p[1], z = p[2];
    sR[i] = make_float4(x, y, z, x*x + y*y + z*z);
    const float* q = gt + ((size_t)b * NH + i) * 3;
    float gx = q[0], gy = q[1], gz = q[2];
    sG[i] = make_float4(gx, gy, gz, gx*gx + gy*gy + gz*gz);
  }
  __syncthreads();
  const int o = tile * 256 + tid;
  float penetr = 0.f, nptsv = 0.f, contactv = 0.f, consistv = 0.f, lossov = 0.f;
  if (o < NO) {
    const float* op = obj + ((size_t)b * NO + o) * 3;
    const float ox = op[0], oy = op[1], oz = op[2];
    const float nx = -2.f*ox, ny = -2.f*oy, nz = -2.f*oz;
    const float o2 = ox*ox + oy*oy + oz*oz;
    float bR = 3.4e38f, bG = 3.4e38f; int iR = 0, iG = 0;
    for (int i = 0; i < NH; ++i) {
      float4 h = sR[i];
      float t = fmaf(nx, h.x, h.w); t = fmaf(ny, h.y, t); t = fmaf(nz, h.z, t);
      if (t < bR) { bR = t; iR = i; }
      float4 g = sG[i];
      float u = fmaf(nx, g.x, g.w); u = fmaf(ny, g.y, u); u = fmaf(nz, g.z, u);
      if (u < bG) { bG = u; iG = i; }
    }
    float bP = 3.4e38f;
    for (int k = 0; k < NP; ++k) {
      float4 h = sR[c_prior[k]];
      float t = fmaf(nx, h.x, h.w); t = fmaf(ny, h.y, t); t = fmaf(nz, h.z, t);
      bP = fminf(bP, t);
    }
    float d2R = fmaxf(bR + o2, 0.f);
    float d2G = fmaxf(bG + o2, 0.f);
    float d2P = fmaxf(bP + o2, 0.f);
    float4 hR = sR[iR];
    const float* nR = rnorm + ((size_t)b * NH + iR) * 3;
    float dotR = (ox-hR.x)*nR[0] + (oy-hR.y)*nR[1] + (oz-hR.z)*nR[2];
    float4 hG = sG[iG];
    const float* nG = gnorm + ((size_t)b * NH + iG) * 3;
    float dotG = (ox-hG.x)*nG[0] + (oy-hG.y)*nG[1] + (oz-hG.z)*nG[2];
    float sgnR = (dotR > 0.f) ? 1.f : ((dotR < 0.f) ? -1.f : 0.f);
    float sgnG = (dotG > 0.f) ? 1.f : ((dotG < 0.f) ? -1.f : 0.f);
    float sR_ = sqrtf(d2R), sG_ = sqrtf(d2G);
    float o2h = sR_*sgnR, o2hg = sG_*sgnG;
    bool interior = dotR < 0.f;
    bool cmap = sG_ < 0.005f, rcmap = sR_ < 0.005f;
    penetr = interior ? d2R : 0.f;
    nptsv = cmap ? 1.f : 0.f;
    contactv = cmap ? d2P : 0.f;
    consistv = (cmap && rcmap) ? 1.f : 0.f;
    float w = (o2h < 0.f) ? 1.5f : (((o2hg < 0.01f) && (o2hg > -0.005f)) ? 1.f : 0.1f);
    lossov = fabsf(o2h - o2hg) * w;
  }
  float vals[5] = {penetr, nptsv, contactv, consistv, lossov};
  const int lane = tid & 63, wv = tid >> 6;
  for (int q = 0; q < 5; ++q) {
    float s = wave_sum(vals[q]);
    if (lane == 0) red[wv][q] = s;
  }
  __syncthreads();
  if (tid < 5) {
    float s = red[0][tid] + red[1][tid] + red[2][tid] + red[3][tid];
    atomicAdd(&accs[tid * ACC_STRIDE], s);
  }
}

__global__ __launch_bounds__(256) void hand_full(
    const float* __restrict__ recon, const float* __restrict__ gt,
    const float* __restrict__ obj, const float* __restrict__ vw,
    float* __restrict__ accs)
{
  __shared__ float4 sO[500];
  __shared__ float red[4];
  const int b = blockIdx.x >> 2;
  const int j = ((blockIdx.x & 3) << 8) + threadIdx.x;
  const bool valid = j < NH;
  float rx=0,ry=0,rz=0,gx=0,gy=0,gz=0;
  if (valid) {
    const float* rp = recon + ((size_t)b * NH + j) * 3;
    const float* gp = gt + ((size_t)b * NH + j) * 3;
    rx=rp[0];ry=rp[1];rz=rp[2]; gx=gp[0];gy=gp[1];gz=gp[2];
  }
  const float nrx=-2.f*rx, nry=-2.f*ry, nrz=-2.f*rz;
  const float ngx=-2.f*gx, ngy=-2.f*gy, ngz=-2.f*gz;
  const float r2 = rx*rx+ry*ry+rz*rz, g2 = gx*gx+gy*gy+gz*gz;
  float mR = 3.4e38f, mG = 3.4e38f;
  for (int oc = 0; oc < 6; ++oc) {
    __syncthreads();
    const float* Ob = obj + ((size_t)b * NO + oc * 500) * 3;
    for (int i = threadIdx.x; i < 500; i += 256) {
      float x = Ob[3*i], y = Ob[3*i+1], z = Ob[3*i+2];
      sO[i] = make_float4(x, y, z, x*x + y*y + z*z);
    }
    __syncthreads();
    if (valid) {
      for (int k = 0; k < 500; ++k) {
        float4 o4 = sO[k];
        float t = fmaf(nrx,o4.x,o4.w); t = fmaf(nry,o4.y,t); t = fmaf(nrz,o4.z,t);
        mR = fminf(mR, t);
        float u = fmaf(ngx,o4.x,o4.w); u = fmaf(ngy,o4.y,u); u = fmaf(ngz,o4.z,u);
        mG = fminf(mG, u);
      }
    }
  }
  float lossh = valid ? fabsf(sqrtf(fmaxf(mR+r2,0.f)) - sqrtf(fmaxf(mG+g2,0.f))) * powf(vw[j], 0.4f) : 0.f;
  const int lane = threadIdx.x & 63, wv = threadIdx.x >> 6;
  float s = wave_sum(lossh);
  if (lane == 0) red[wv] = s;
  __syncthreads();
  if (threadIdx.x == 0) atomicAdd(&accs[5 * ACC_STRIDE], red[0]+red[1]+red[2]+red[3]);
}

__global__ __launch_bounds__(256) void tail_nomins(
    const float* __restrict__ recon, const float* __restrict__ gt,
    const float* __restrict__ mean, const float* __restrict__ logv,
    float* __restrict__ accs)
{
  __shared__ float red[4][2];
  const int t = blockIdx.x * 256 + threadIdx.x;
  float rsum = 0.f, ksum = 0.f;
  if (t < NB * NH) {
    const float* rp = recon + (size_t)t * 3;
    const float* gp = gt + (size_t)t * 3;
    float d0 = rp[0]-gp[0], d1 = rp[1]-gp[1], d2 = rp[2]-gp[2];
    rsum = d0*d0 + d1*d1 + d2*d2;
  }
  if (t < NB * NZ) {
    float m = mean[t], lv = logv[t];
    ksum = 1.f + lv - m*m - expf(lv);
  }
  float vals[2] = {rsum, ksum};
  const int lane = threadIdx.x & 63, wv = threadIdx.x >> 6;
  for (int q = 0; q < 2; ++q) {
    float s = wave_sum(vals[q]);
    if (lane == 0) red[wv][q] = s;
  }
  __syncthreads();
  if (threadIdx.x < 2) {
    float s = red[0][threadIdx.x] + red[1][threadIdx.x] + red[2][threadIdx.x] + red[3][threadIdx.x];
    atomicAdd(&accs[(6 + threadIdx.x) * ACC_STRIDE], s);
  }
}

__global__ void init_small(float* accs) {
  int t = threadIdx.x;
  accs[t] = 0.0f;
  accs[t + 256] = 0.0f;
}

extern "C" void kernel_launch(void* const* d_in, const int* in_sizes, int n_in,
                              void* d_out, int out_size, void* d_ws, size_t ws_size,
                              hipStream_t stream) {
  const float* recon = (const float*)d_in[0];
  const float* gt    = (const float*)d_in[1];
  const float* rnorm = (const float*)d_in[2];
  const float* gnorm = (const float*)d_in[3];
  const float* obj   = (const float*)d_in[4];
  const float* mean  = (const float*)d_in[5];
  const float* logv  = (const float*)d_in[6];
  const float* vw    = (const float*)d_in[7];
  float* out = (float*)d_out;

  // ws: padded accs[512] @0 (2048B) | keyR[8N] keyG[8N] priorK[8N]
  //     minHR[24H] minHG[24H]
  float* accs = (float*)d_ws;
  float* base = (float*)((char*)d_ws + ACC_FLOATS * sizeof(float));

  const size_t needed = ACC_FLOATS * sizeof(float)
                      + (3ull * JS8 * NKEY + 2ull * HC24 * NHT) * sizeof(float);

  if (ws_size >= needed) {
    float* keyR   = base;
    float* keyG   = keyR + (size_t)JS8 * NKEY;
    float* priorK = keyG + (size_t)JS8 * NKEY;
    float* minHR  = priorK + (size_t)JS8 * NKEY;
    float* minHG  = minHR + (size_t)HC24 * NHT;
    const int g1 = NB * OBJ_TILES * JS8 + NB * HC24;   // 768 + 768 = 1536
    mega1t<<<g1, 256, 0, stream>>>(
        recon, gt, obj, keyR, keyG, priorK, minHR, minHG, accs);
    mega2n<<<FIN_BLKS, 256, 0, stream>>>(
        recon, gt, rnorm, gnorm, obj, mean, logv, vw,
        keyR, keyG, priorK, minHR, minHG, accs);
    final_fb<<<1, 1, 0, stream>>>(accs, out);
  } else {
    init_small<<<1, 256, 0, stream>>>(accs);
    obj_mono<<<NB * 12, 256, 0, stream>>>(recon, gt, rnorm, gnorm, obj, accs);
    hand_full<<<NB * 4, 256, 0, stream>>>(recon, gt, obj, vw, accs);
    tail_nomins<<<(NB * NH + 255) / 256, 256, 0, stream>>>(recon, gt, mean, logv, accs);
    final_fb<<<1, 1, 0, stream>>>(accs, out);
  }
}

// Round 7
// 108.361 us; speedup vs baseline: 1.3111x; 1.0667x over previous
//
#include <hip/hip_runtime.h>
#include <math.h>

// GraspCVAE loss, MI355X — round 15.
// R14 post-mortem: -3.2us (fence/counter ~6us gross). Budget now closes:
// 115.6 = fill(43, harness ws-poison, untouchable) + mega1(~42, all
// throughput theories falsified) + mega2(~26) + final(~4).
// mega2 is the untouched piece: 14MB of reads but 26us -> LATENCY-bound
// (482 blocks = 2/CU, 24-48 scattered loads/thread, no TLP).
// R15 attacks mega2: (1) 64-thr blocks -> 1893 blocks, ~7.4 waves/CU;
// (2) JS=4 / HC=12 (mega1-neutral per R10) -> slice fan-in halved (12 obj
// loads, 24 tail loads); (3) atomics spread over 32 sub-lines per slot
// (bid&31) -> max chain 47 not 1504. mega1 logic unchanged; no fences.
// Predict: mega2 26 -> 10-14, total 115.6 -> ~100-106. Neutral => only
// lever left is fused both-axes distance matrix for mega1, or roofline.

#define NB 32
#define NH 778
#define NO 3000
#define NZ 64
#define NP 204

#define P_OBJ 4
#define OBJ_PTS 1024
#define OBJ_TILES 3                   // ceil(3000/1024)
#define JS4 4
#define JC4 195                       // ceil(778/4)
#define HC12 12
#define HCS12 250                     // 3000/12

#define NKEY (NB * NO)                // 96000
#define NHT  (NB * NH)                // 24896

#define M2_OBJ_BLKS (NB * 47)         // 1504 (47*64=3008 >= 3000)
#define M2_TAIL_BLKS (NB * NH / 64)   // 389 (exact: 24896/64)
#define M2_BLKS (M2_OBJ_BLKS + M2_TAIL_BLKS)  // 1893

// accumulator grid: slot q in [0,9), sub-line s in [0,32), each own 128B line
#define ACCIDX(q, s) ((((q) * 32) + (s)) * 32)
#define ACC_FLOATS (9 * 32 * 32)      // 9216 floats = 36 KB

typedef unsigned int uint32;

// original order (used by PATH C)
__device__ __constant__ int c_prior[NP] = {
  697,698,699,700,712,713,714,715,737,738,739,740,741,743,744,745,746,748,749,750,
  753,754,755,756,757,758,759,760,761,762,763,764,765,766,767,768,
  46,47,48,49,164,165,166,167,194,195,223,237,238,280,281,298,301,317,320,323,
  324,325,326,327,328,329,330,331,332,333,340,341,342,343,344,345,346,347,348,349,
  350,351,352,353,354,355,
  356,357,358,359,375,376,386,387,396,397,402,403,413,429,433,434,435,436,437,438,
  439,440,441,442,443,444,452,453,454,455,456,459,460,461,462,463,464,465,466,467,
  468,469,470,471,484,485,486,496,497,506,507,513,514,524,545,546,547,548,549,550,
  551,552,553,555,563,564,565,566,567,570,572,573,574,575,576,577,578,
  580,581,582,583,600,601,602,614,615,624,625,630,631,641,663,664,665,666,667,668,
  670,672,680,681,682,683,684,686,687,688,689,690,691,692,693,694,695,
  73,96,98,99,772,774,775,777
};

// globally ascending sorted prior list
__device__ __constant__ int c_prior_sorted[NP] = {
  46,47,48,49,73,96,98,99,164,165,166,167,194,
  195,223,237,238,280,281,298,301,317,320,323,324,325,326,327,328,329,330,331,
  332,333,340,341,342,343,344,345,346,347,348,349,350,351,352,353,354,355,356,
  357,358,359,375,376,386,387,
  396,397,402,403,413,429,433,434,435,436,437,438,439,440,441,442,443,444,452,
  453,454,455,456,459,460,461,462,463,464,465,466,467,468,469,470,471,484,485,
  486,496,497,506,507,513,514,524,545,546,547,548,549,550,551,552,553,555,563,
  564,565,566,567,570,572,573,574,575,576,577,578,580,581,582,583,
  600,601,602,614,615,624,625,630,631,641,663,664,665,666,667,668,670,672,680,
  681,682,683,684,686,687,688,689,690,691,692,693,694,695,697,698,699,700,712,
  713,714,715,737,738,739,740,741,743,744,745,746,748,749,750,753,754,755,756,
  757,758,759,760,761,762,763,764,765,766,767,768,772,774,775,777
};
// position ranges in c_prior_sorted for j in [s*195, (s+1)*195)
__device__ __constant__ int c_psplit4[5] = {0, 13, 58, 131, 204};

__device__ inline float wave_sum(float v) {
  v += __shfl_down(v, 32);
  v += __shfl_down(v, 16);
  v += __shfl_down(v, 8);
  v += __shfl_down(v, 4);
  v += __shfl_down(v, 2);
  v += __shfl_down(v, 1);
  return v;
}

// forced 3-operand VALU ops (R9: verified correct)
__device__ __forceinline__ float f_min3(float a, float b, float c) {
  float r;
  asm("v_min3_f32 %0, %1, %2, %3" : "=v"(r) : "v"(a), "v"(b), "v"(c));
  return r;
}
__device__ __forceinline__ float f_packao(float t, int j, uint32 mask) {
  float r;
  asm("v_and_or_b32 %0, %1, %2, %3" : "=v"(r) : "v"(t), "s"(mask), "v"(j));
  return r;
}

// ======================= dispatch 1: mega1 (tier-A geometry) =================
// blocks [0, 384): obj->hand NN (3 tiles x 4 splits); [384, 768): hand->obj.
__global__ __launch_bounds__(256) void mega1t(
    const float* __restrict__ recon, const float* __restrict__ gt,
    const float* __restrict__ obj,
    float* __restrict__ keyR, float* __restrict__ keyG,
    float* __restrict__ priorK,
    float* __restrict__ minHR, float* __restrict__ minHG,
    float* __restrict__ accs)
{
  const int OBJ_B = NB * OBJ_TILES * JS4;   // 384
  const int bid = blockIdx.x;
  const int tid = threadIdx.x;
  const uint32 KMASK = 0xFFFFFC00u;

  if (bid == 0) {  // zero the 36KB accumulator grid (consumed after boundary)
    for (int i = tid; i < ACC_FLOATS; i += 256) accs[i] = 0.0f;
  }

  if (bid < OBJ_B) {
    // ---- obj -> hand NN (j-split 4) + in-pass partial prior-NN ----
    __shared__ float4 shA[JC4];   // recon split
    __shared__ float4 shB[JC4];   // gt split
    const int b     = bid / (OBJ_TILES * JS4);
    const int rem   = bid % (OBJ_TILES * JS4);
    const int tile  = rem / JS4;
    const int split = rem % JS4;
    const int jbase = split * JC4;
    const int jcnt  = (NH - jbase < JC4) ? (NH - jbase) : JC4;  // 195 or 193

    for (int i = tid; i < jcnt; i += 256) {
      const float* p = recon + ((size_t)b * NH + jbase + i) * 3;
      float x = p[0], y = p[1], z = p[2];
      shA[i] = make_float4(x, y, z, x*x + y*y + z*z);
      const float* q = gt + ((size_t)b * NH + jbase + i) * 3;
      float gx = q[0], gy = q[1], gz = q[2];
      shB[i] = make_float4(gx, gy, gz, gx*gx + gy*gy + gz*gz);
    }
    __syncthreads();

    float nx[P_OBJ], ny[P_OBJ], nz[P_OBJ];
    int ob[P_OBJ]; bool val[P_OBJ];
    #pragma unroll
    for (int m = 0; m < P_OBJ; ++m) {
      int o = tile * OBJ_PTS + m * 256 + tid;
      ob[m] = o; val[m] = (o < NO);
      float x = 0.f, y = 0.f, z = 0.f;
      if (val[m]) {
        const float* op = obj + ((size_t)b * NO + o) * 3;
        x = op[0]; y = op[1]; z = op[2];
      }
      nx[m] = -2.f * x; ny[m] = -2.f * y; nz[m] = -2.f * z;
    }

    float bR[P_OBJ], bG[P_OBJ];
    #pragma unroll
    for (int m = 0; m < P_OBJ; ++m) { bR[m] = 3.4e38f; bG[m] = 3.4e38f; }

#define RSTEP(hh0, hh1, jj0, jj1) \
    { _Pragma("unroll") for (int m = 0; m < P_OBJ; ++m) { \
        float t0 = fmaf(nx[m], hh0.x, hh0.w); t0 = fmaf(ny[m], hh0.y, t0); t0 = fmaf(nz[m], hh0.z, t0); \
        float t1 = fmaf(nx[m], hh1.x, hh1.w); t1 = fmaf(ny[m], hh1.y, t1); t1 = fmaf(nz[m], hh1.z, t1); \
        bR[m] = f_min3(bR[m], f_packao(t0, jj0, KMASK), f_packao(t1, jj1, KMASK)); } }
#define GSTEP(gg0, gg1, jj0, jj1) \
    { _Pragma("unroll") for (int m = 0; m < P_OBJ; ++m) { \
        float u0 = fmaf(nx[m], gg0.x, gg0.w); u0 = fmaf(ny[m], gg0.y, u0); u0 = fmaf(nz[m], gg0.z, u0); \
        float u1 = fmaf(nx[m], gg1.x, gg1.w); u1 = fmaf(ny[m], gg1.y, u1); u1 = fmaf(nz[m], gg1.z, u1); \
        bG[m] = f_min3(bG[m], f_packao(u0, jj0, KMASK), f_packao(u1, jj1, KMASK)); } }

    // interleaved prefetch: every LDS read pair covered by a VALU phase
    float4 h0 = shA[0], h1 = shA[1];
    int i = 0;
    for (; i + 3 < jcnt; i += 2) {
      float4 g0 = shB[i], g1 = shB[i + 1];
      RSTEP(h0, h1, jbase + i, jbase + i + 1);
      float4 hn0 = shA[i + 2], hn1 = shA[i + 3];
      GSTEP(g0, g1, jbase + i, jbase + i + 1);
      h0 = hn0; h1 = hn1;
    }
    {
      float4 g0 = shB[i], g1 = shB[i + 1];
      RSTEP(h0, h1, jbase + i, jbase + i + 1);
      GSTEP(g0, g1, jbase + i, jbase + i + 1);
      i += 2;
    }
    for (; i < jcnt; ++i) {       // odd jcnt (195/193): one leftover
      float4 hh = shA[i], gg = shB[i];
      #pragma unroll
      for (int m = 0; m < P_OBJ; ++m) {
        float t0 = fmaf(nx[m], hh.x, hh.w); t0 = fmaf(ny[m], hh.y, t0); t0 = fmaf(nz[m], hh.z, t0);
        bR[m] = fminf(bR[m], f_packao(t0, jbase + i, KMASK));
        float u0 = fmaf(nx[m], gg.x, gg.w); u0 = fmaf(ny[m], gg.y, u0); u0 = fmaf(nz[m], gg.z, u0);
        bG[m] = fminf(bG[m], f_packao(u0, jbase + i, KMASK));
      }
    }
#undef RSTEP
#undef GSTEP

    // partial prior-NN over this split's prior members (candidates in shA)
    float bP[P_OBJ];
    #pragma unroll
    for (int m = 0; m < P_OBJ; ++m) bP[m] = 3.4e38f;
    const int pk0 = c_psplit4[split], pk1 = c_psplit4[split + 1];
    int k = pk0;
    for (; k + 1 < pk1; k += 2) {
      float4 ha = shA[c_prior_sorted[k] - jbase];
      float4 hb = shA[c_prior_sorted[k + 1] - jbase];
      #pragma unroll
      for (int m = 0; m < P_OBJ; ++m) {
        float t = fmaf(nx[m], ha.x, ha.w); t = fmaf(ny[m], ha.y, t); t = fmaf(nz[m], ha.z, t);
        float u = fmaf(nx[m], hb.x, hb.w); u = fmaf(ny[m], hb.y, u); u = fmaf(nz[m], hb.z, u);
        bP[m] = f_min3(bP[m], t, u);
      }
    }
    if (k < pk1) {
      float4 ha = shA[c_prior_sorted[k] - jbase];
      #pragma unroll
      for (int m = 0; m < P_OBJ; ++m) {
        float t = fmaf(nx[m], ha.x, ha.w); t = fmaf(ny[m], ha.y, t); t = fmaf(nz[m], ha.z, t);
        bP[m] = fminf(bP[m], t);
      }
    }

    #pragma unroll
    for (int m = 0; m < P_OBJ; ++m) {
      if (!val[m]) continue;
      const size_t idx = (size_t)split * NKEY + (size_t)b * NO + ob[m];
      keyR[idx] = bR[m];
      keyG[idx] = bG[m];
      priorK[idx] = bP[m];
    }
  } else {
    // ---- hand -> obj NN, 12 chunks of 250; prefetch + rotating tail ----
    __shared__ float4 sO[HCS12];
    const int bid2 = bid - OBJ_B;
    const int oc = bid2 % HC12;
    const int b  = bid2 / HC12;

    const float* Ob = obj + ((size_t)b * NO + oc * HCS12) * 3;
    for (int i2 = tid; i2 < HCS12; i2 += 256) {
      float x = Ob[3*i2], y = Ob[3*i2+1], z = Ob[3*i2+2];
      sO[i2] = make_float4(x, y, z, x*x + y*y + z*z);
    }
    __syncthreads();

    float nrx[3], nry[3], nrz[3];
    float ngx[3], ngy[3], ngz[3];
    #pragma unroll
    for (int m = 0; m < 3; ++m) {
      const int j = m * 256 + tid;                 // 0..767, always valid
      const float* rp = recon + ((size_t)b * NH + j) * 3;
      const float* gp = gt    + ((size_t)b * NH + j) * 3;
      nrx[m] = -2.f*rp[0]; nry[m] = -2.f*rp[1]; nrz[m] = -2.f*rp[2];
      ngx[m] = -2.f*gp[0]; ngy[m] = -2.f*gp[1]; ngz[m] = -2.f*gp[2];
    }

    float mR[3], mG[3];
    #pragma unroll
    for (int m = 0; m < 3; ++m) { mR[m] = 3.4e38f; mG[m] = 3.4e38f; }

#define HSTEP(oo0, oo1) \
    { _Pragma("unroll") for (int m = 0; m < 3; ++m) { \
        float t0 = fmaf(nrx[m], oo0.x, oo0.w); t0 = fmaf(nry[m], oo0.y, t0); t0 = fmaf(nrz[m], oo0.z, t0); \
        float t1 = fmaf(nrx[m], oo1.x, oo1.w); t1 = fmaf(nry[m], oo1.y, t1); t1 = fmaf(nrz[m], oo1.z, t1); \
        mR[m] = f_min3(mR[m], t0, t1); \
        float u0 = fmaf(ngx[m], oo0.x, oo0.w); u0 = fmaf(ngy[m], oo0.y, u0); u0 = fmaf(ngz[m], oo0.z, u0); \
        float u1 = fmaf(ngx[m], oo1.x, oo1.w); u1 = fmaf(ngy[m], oo1.y, u1); u1 = fmaf(ngz[m], oo1.z, u1); \
        mG[m] = f_min3(mG[m], u0, u1); } }

    float4 o0 = sO[0], o1 = sO[1];
    int k2 = 0;
    for (; k2 + 3 < HCS12; k2 += 2) {
      float4 a0 = sO[k2 + 2], a1 = sO[k2 + 3];
      HSTEP(o0, o1);
      o0 = a0; o1 = a1;
    }
    HSTEP(o0, o1);                  // last preloaded pair (HCS12=250 even)
    k2 += 2;
    for (; k2 < HCS12; ++k2) {      // none for even HCS12
      float4 oc4 = sO[k2];
      #pragma unroll
      for (int m = 0; m < 3; ++m) {
        float t0 = fmaf(nrx[m], oc4.x, oc4.w); t0 = fmaf(nry[m], oc4.y, t0); t0 = fmaf(nrz[m], oc4.z, t0);
        mR[m] = fminf(mR[m], t0);
        float u0 = fmaf(ngx[m], oc4.x, oc4.w); u0 = fmaf(ngy[m], oc4.y, u0); u0 = fmaf(ngz[m], oc4.z, u0);
        mG[m] = fminf(mG[m], u0);
      }
    }
#undef HSTEP

    #pragma unroll
    for (int m = 0; m < 3; ++m) {
      const int j = m * 256 + tid;
      const size_t idx = (size_t)oc * NHT + (size_t)b * NH + j;
      minHR[idx] = mR[m];
      minHG[idx] = mG[m];
    }

    // tail: hand points 768..777 on one wave, rotated per block
    const int tw = bid2 & 3;
    if ((tid >> 6) == tw) {
      const int j3 = 768 + (tid & 63);
      const bool v3 = (j3 < NH);                   // lanes 0..9
      float rx=0.f,ry=0.f,rz=0.f,gx=0.f,gy=0.f,gz=0.f;
      if (v3) {
        const float* rp = recon + ((size_t)b * NH + j3) * 3;
        const float* gp = gt    + ((size_t)b * NH + j3) * 3;
        rx=rp[0];ry=rp[1];rz=rp[2]; gx=gp[0];gy=gp[1];gz=gp[2];
      }
      const float n3rx=-2.f*rx, n3ry=-2.f*ry, n3rz=-2.f*rz;
      const float n3gx=-2.f*gx, n3gy=-2.f*gy, n3gz=-2.f*gz;
      float m3R = 3.4e38f, m3G = 3.4e38f;
      int k3 = 0;
      for (; k3 + 1 < HCS12; k3 += 2) {
        float4 q0 = sO[k3], q1 = sO[k3 + 1];
        float t0 = fmaf(n3rx, q0.x, q0.w); t0 = fmaf(n3ry, q0.y, t0); t0 = fmaf(n3rz, q0.z, t0);
        float t1 = fmaf(n3rx, q1.x, q1.w); t1 = fmaf(n3ry, q1.y, t1); t1 = fmaf(n3rz, q1.z, t1);
        m3R = f_min3(m3R, t0, t1);
        float u0 = fmaf(n3gx, q0.x, q0.w); u0 = fmaf(n3gy, q0.y, u0); u0 = fmaf(n3gz, q0.z, u0);
        float u1 = fmaf(n3gx, q1.x, q1.w); u1 = fmaf(n3gy, q1.y, u1); u1 = fmaf(n3gz, q1.z, u1);
        m3G = f_min3(m3G, u0, u1);
      }
      if (HCS12 & 1) {              // false for 250; kept for generality
        float4 q0 = sO[HCS12 - 1];
        float t0 = fmaf(n3rx, q0.x, q0.w); t0 = fmaf(n3ry, q0.y, t0); t0 = fmaf(n3rz, q0.z, t0);
        m3R = fminf(m3R, t0);
        float u0 = fmaf(n3gx, q0.x, q0.w); u0 = fmaf(n3gy, q0.y, u0); u0 = fmaf(n3gz, q0.z, u0);
        m3G = fminf(m3G, u0);
      }
      if (v3) {
        const size_t idx = (size_t)oc * NHT + (size_t)b * NH + j3;
        minHR[idx] = m3R;
        minHG[idx] = m3G;
      }
    }
  }
}

// ======================= dispatch 2: mega2 (64-thr, no fence) ===============
__global__ __launch_bounds__(64) void mega2s(
    const float* __restrict__ recon, const float* __restrict__ gt,
    const float* __restrict__ rnorm, const float* __restrict__ gnorm,
    const float* __restrict__ obj,
    const float* __restrict__ mean, const float* __restrict__ logv,
    const float* __restrict__ vw,
    const float* __restrict__ keyR, const float* __restrict__ keyG,
    const float* __restrict__ priorK,
    const float* __restrict__ minHR, const float* __restrict__ minHG,
    float* __restrict__ accs)
{
  const int bid = blockIdx.x;
  const int tid = threadIdx.x;
  const int line = bid & 31;

  if (bid < M2_OBJ_BLKS) {
    const int b = bid / 47;
    const int o = (bid % 47) * 64 + tid;
    float penetr = 0.f, nptsv = 0.f, contactv = 0.f, consistv = 0.f, lossov = 0.f;
    if (o < NO) {
      const float* op = obj + ((size_t)b * NO + o) * 3;
      const float ox = op[0], oy = op[1], oz = op[2];
      const float o2 = ox*ox + oy*oy + oz*oz;
      const size_t base = (size_t)b * NO + o;

      float kR = 3.4e38f, kG = 3.4e38f, bP = 3.4e38f;
      #pragma unroll
      for (int s = 0; s < JS4; ++s) {
        kR = fminf(kR, keyR[(size_t)s * NKEY + base]);
        kG = fminf(kG, keyG[(size_t)s * NKEY + base]);
        bP = fminf(bP, priorK[(size_t)s * NKEY + base]);
      }
      uint32 kRb = __float_as_uint(kR), kGb = __float_as_uint(kG);
      int idxR = (int)(kRb & 0x3FFu), idxG = (int)(kGb & 0x3FFu);
      float d2R = fmaxf(__uint_as_float(kRb & 0xFFFFFC00u) + o2, 0.f);
      float d2G = fmaxf(__uint_as_float(kGb & 0xFFFFFC00u) + o2, 0.f);
      float d2P = fmaxf(bP + o2, 0.f);

      const float* hR = recon + ((size_t)b * NH + idxR) * 3;
      const float* nR = rnorm + ((size_t)b * NH + idxR) * 3;
      float dotR = (ox - hR[0]) * nR[0] + (oy - hR[1]) * nR[1] + (oz - hR[2]) * nR[2];
      const float* hG = gt + ((size_t)b * NH + idxG) * 3;
      const float* nG = gnorm + ((size_t)b * NH + idxG) * 3;
      float dotG = (ox - hG[0]) * nG[0] + (oy - hG[1]) * nG[1] + (oz - hG[2]) * nG[2];

      float sgnR = (dotR > 0.f) ? 1.f : ((dotR < 0.f) ? -1.f : 0.f);
      float sgnG = (dotG > 0.f) ? 1.f : ((dotG < 0.f) ? -1.f : 0.f);
      float sR_ = sqrtf(d2R), sG_ = sqrtf(d2G);
      float o2h = sR_ * sgnR, o2hg = sG_ * sgnG;

      bool interior = dotR < 0.f;
      bool cmap = sG_ < 0.005f;
      bool rcmap = sR_ < 0.005f;

      penetr   = interior ? d2R : 0.f;
      nptsv    = cmap ? 1.f : 0.f;
      contactv = cmap ? d2P : 0.f;
      consistv = (cmap && rcmap) ? 1.f : 0.f;
      float w = (o2h < 0.f) ? 1.5f
              : (((o2hg < 0.01f) && (o2hg > -0.005f)) ? 1.f : 0.1f);
      lossov = fabsf(o2h - o2hg) * w;
    }

    float vals[5] = {penetr, nptsv, contactv, consistv, lossov};
    #pragma unroll
    for (int q = 0; q < 5; ++q) {
      float s = wave_sum(vals[q]);
      if (tid == 0) atomicAdd(&accs[ACCIDX(q, line)], s);
    }
  } else {
    const int t = (bid - M2_OBJ_BLKS) * 64 + tid;   // exact: 389*64 = 24896
    float lossh = 0.f, rsum = 0.f, ksum = 0.f;
    {
      const float* rp = recon + (size_t)t * 3;
      const float* gp = gt + (size_t)t * 3;
      float rx = rp[0], ry = rp[1], rz = rp[2];
      float gx = gp[0], gy = gp[1], gz = gp[2];
      float d0 = rx - gx, d1 = ry - gy, d2 = rz - gz;
      rsum = d0*d0 + d1*d1 + d2*d2;

      float mRt = 3.4e38f, mGt = 3.4e38f;
      #pragma unroll
      for (int c = 0; c < HC12; ++c) {
        mRt = fminf(mRt, minHR[(size_t)c * NHT + t]);
        mGt = fminf(mGt, minHG[(size_t)c * NHT + t]);
      }
      float r2 = rx*rx + ry*ry + rz*rz;
      float g2 = gx*gx + gy*gy + gz*gz;
      float d2Rh = fmaxf(mRt + r2, 0.f);
      float d2Gh = fmaxf(mGt + g2, 0.f);
      int j = t % NH;
      lossh = fabsf(sqrtf(d2Rh) - sqrtf(d2Gh)) * powf(vw[j], 0.4f);
    }
    if (t < NB * NZ) {
      float m = mean[t], lv = logv[t];
      ksum = 1.f + lv - m * m - expf(lv);
    }
    float vals[3] = {lossh, rsum, ksum};
    #pragma unroll
    for (int q = 0; q < 3; ++q) {
      float s = wave_sum(vals[q]);
      if (tid == 0) atomicAdd(&accs[ACCIDX(5 + q, line)], s);
    }
  }
  // no fence, no counter — kernel boundary orders everything
}

// ======================= dispatch 3: final combine =======================
__global__ void final_fb(const float* __restrict__ a, float* __restrict__ out) {
  __shared__ float sums[8];
  const int q = threadIdx.x;
  if (q < 8) {
    float s = 0.f;
    for (int l = 0; l < 32; ++l) s += a[ACCIDX(q, l)];
    sums[q] = s;
  }
  __syncthreads();
  if (threadIdx.x == 0) {
    const float recon_loss = sums[6] / (float)NB;
    const float kld = -0.5f * sums[7] / (float)NB * 10.f;
    const float penetr = 100.f * sums[0] / (float)NB;
    const float npts = sums[1];
    const float contact = (npts > 0.f) ? (3000.f * sums[2] / ((float)NB * npts)) : 0.f;
    const float consistency = -5.f * sums[3] / (npts + 0.0001f);
    const float lossh = 35.f * (1.f - 0.005f) * (sums[5] / (float)(NB * NH));
    const float losso = 30.f * (1.f - 0.005f) * (sums[4] / (float)(NB * NO));
    out[0] = recon_loss + 0.1f * kld + 1000.f * penetr + 10.f * contact
           + 10.f * consistency + lossh + losso;
  }
}

// =========================== PATH C (tiny ws fallback) ===========================
__global__ __launch_bounds__(256) void obj_mono(
    const float* __restrict__ recon, const float* __restrict__ gt,
    const float* __restrict__ rnorm, const float* __restrict__ gnorm,
    const float* __restrict__ obj, float* __restrict__ accs)
{
  __shared__ float4 sR[NH];
  __shared__ float4 sG[NH];
  __shared__ float red[4][5];
  const int b = blockIdx.x / 12;
  const int tile = blockIdx.x % 12;
  const int tid = threadIdx.x;
  for (int i = tid; i < NH; i += 256) {
    const float* p = recon + ((size_t)b * NH + i) * 3;
    float x = p[0], y = p[1], z = p[2];
    sR[i] = make_float4(x, y, z, x*x + y*y + z*z);
    const float* q = gt + ((size_t)b * NH + i) * 3;
    float gx = q[0], gy = q[1], gz = q[2];
    sG[i] = make_float4(gx, gy, gz, gx*gx + gy*gy + gz*gz);
  }
  __syncthreads();
  const int o = tile * 256 + tid;
  float penetr = 0.f, nptsv = 0.f, contactv = 0.f, consistv = 0.f, lossov = 0.f;
  if (o < NO) {
    const float* op = obj + ((size_t)b * NO + o) * 3;
    const float ox = op[0], oy = op[1], oz = op[2];
    const float nx = -2.f*ox, ny = -2.f*oy, nz = -2.f*oz;
    const float o2 = ox*ox + oy*oy + oz*oz;
    float bR = 3.4e38f, bG = 3.4e38f; int iR = 0, iG = 0;
    for (int i = 0; i < NH; ++i) {
      float4 h = sR[i];
      float t = fmaf(nx, h.x, h.w); t = fmaf(ny, h.y, t); t = fmaf(nz, h.z, t);
      if (t < bR) { bR = t; iR = i; }
      float4 g = sG[i];
      float u = fmaf(nx, g.x, g.w); u = fmaf(ny, g.y, u); u = fmaf(nz, g.z, u);
      if (u < bG) { bG = u; iG = i; }
    }
    float bP = 3.4e38f;
    for (int k = 0; k < NP; ++k) {
      float4 h = sR[c_prior[k]];
      float t = fmaf(nx, h.x, h.w); t = fmaf(ny, h.y, t); t = fmaf(nz, h.z, t);
      bP = fminf(bP, t);
    }
    float d2R = fmaxf(bR + o2, 0.f);
    float d2G = fmaxf(bG + o2, 0.f);
    float d2P = fmaxf(bP + o2, 0.f);
    float4 hR = sR[iR];
    const float* nR = rnorm + ((size_t)b * NH + iR) * 3;
    float dotR = (ox-hR.x)*nR[0] + (oy-hR.y)*nR[1] + (oz-hR.z)*nR[2];
    float4 hG = sG[iG];
    const float* nG = gnorm + ((size_t)b * NH + iG) * 3;
    float dotG = (ox-hG.x)*nG[0] + (oy-hG.y)*nG[1] + (oz-hG.z)*nG[2];
    float sgnR = (dotR > 0.f) ? 1.f : ((dotR < 0.f) ? -1.f : 0.f);
    float sgnG = (dotG > 0.f) ? 1.f : ((dotG < 0.f) ? -1.f : 0.f);
    float sR_ = sqrtf(d2R), sG_ = sqrtf(d2G);
    float o2h = sR_*sgnR, o2hg = sG_*sgnG;
    bool interior = dotR < 0.f;
    bool cmap = sG_ < 0.005f, rcmap = sR_ < 0.005f;
    penetr = interior ? d2R : 0.f;
    nptsv = cmap ? 1.f : 0.f;
    contactv = cmap ? d2P : 0.f;
    consistv = (cmap && rcmap) ? 1.f : 0.f;
    float w = (o2h < 0.f) ? 1.5f : (((o2hg < 0.01f) && (o2hg > -0.005f)) ? 1.f : 0.1f);
    lossov = fabsf(o2h - o2hg) * w;
  }
  float vals[5] = {penetr, nptsv, contactv, consistv, lossov};
  const int lane = tid & 63, wv = tid >> 6;
  for (int q = 0; q < 5; ++q) {
    float s = wave_sum(vals[q]);
    if (lane == 0) red[wv][q] = s;
  }
  __syncthreads();
  if (tid < 5) {
    float s = red[0][tid] + red[1][tid] + red[2][tid] + red[3][tid];
    atomicAdd(&accs[ACCIDX(tid, blockIdx.x & 31)], s);
  }
}

__global__ __launch_bounds__(256) void hand_full(
    const float* __restrict__ recon, const float* __restrict__ gt,
    const float* __restrict__ obj, const float* __restrict__ vw,
    float* __restrict__ accs)
{
  __shared__ float4 sO[500];
  __shared__ float red[4];
  const int b = blockIdx.x >> 2;
  const int j = ((blockIdx.x & 3) << 8) + threadIdx.x;
  const bool valid = j < NH;
  float rx=0,ry=0,rz=0,gx=0,gy=0,gz=0;
  if (valid) {
    const float* rp = recon + ((size_t)b * NH + j) * 3;
    const float* gp = gt + ((size_t)b * NH + j) * 3;
    rx=rp[0];ry=rp[1];rz=rp[2]; gx=gp[0];gy=gp[1];gz=gp[2];
  }
  const float nrx=-2.f*rx, nry=-2.f*ry, nrz=-2.f*rz;
  const float ngx=-2.f*gx, ngy=-2.f*gy, ngz=-2.f*gz;
  const float r2 = rx*rx+ry*ry+rz*rz, g2 = gx*gx+gy*gy+gz*gz;
  float mR = 3.4e38f, mG = 3.4e38f;
  for (int oc = 0; oc < 6; ++oc) {
    __syncthreads();
    const float* Ob = obj + ((size_t)b * NO + oc * 500) * 3;
    for (int i = threadIdx.x; i < 500; i += 256) {
      float x = Ob[3*i], y = Ob[3*i+1], z = Ob[3*i+2];
      sO[i] = make_float4(x, y, z, x*x + y*y + z*z);
    }
    __syncthreads();
    if (valid) {
      for (int k = 0; k < 500; ++k) {
        float4 o4 = sO[k];
        float t = fmaf(nrx,o4.x,o4.w); t = fmaf(nry,o4.y,t); t = fmaf(nrz,o4.z,t);
        mR = fminf(mR, t);
        float u = fmaf(ngx,o4.x,o4.w); u = fmaf(ngy,o4.y,u); u = fmaf(ngz,o4.z,u);
        mG = fminf(mG, u);
      }
    }
  }
  float lossh = valid ? fabsf(sqrtf(fmaxf(mR+r2,0.f)) - sqrtf(fmaxf(mG+g2,0.f))) * powf(vw[j], 0.4f) : 0.f;
  const int lane = threadIdx.x & 63, wv = threadIdx.x >> 6;
  float s = wave_sum(lossh);
  if (lane == 0) red[wv] = s;
  __syncthreads();
  if (threadIdx.x == 0) atomicAdd(&accs[ACCIDX(5, blockIdx.x & 31)], red[0]+red[1]+red[2]+red[3]);
}

__global__ __launch_bounds__(256) void tail_nomins(
    const float* __restrict__ recon, const float* __restrict__ gt,
    const float* __restrict__ mean, const float* __restrict__ logv,
    float* __restrict__ accs)
{
  __shared__ float red[4][2];
  const int t = blockIdx.x * 256 + threadIdx.x;
  float rsum = 0.f, ksum = 0.f;
  if (t < NB * NH) {
    const float* rp = recon + (size_t)t * 3;
    const float* gp = gt + (size_t)t * 3;
    float d0 = rp[0]-gp[0], d1 = rp[1]-gp[1], d2 = rp[2]-gp[2];
    rsum = d0*d0 + d1*d1 + d2*d2;
  }
  if (t < NB * NZ) {
    float m = mean[t], lv = logv[t];
    ksum = 1.f + lv - m*m - expf(lv);
  }
  float vals[2] = {rsum, ksum};
  const int lane = threadIdx.x & 63, wv = threadIdx.x >> 6;
  for (int q = 0; q < 2; ++q) {
    float s = wave_sum(vals[q]);
    if (lane == 0) red[wv][q] = s;
  }
  __syncthreads();
  if (threadIdx.x < 2) {
    float s = red[0][threadIdx.x] + red[1][threadIdx.x] + red[2][threadIdx.x] + red[3][threadIdx.x];
    atomicAdd(&accs[ACCIDX(6 + threadIdx.x, blockIdx.x & 31)], s);
  }
}

__global__ void init_small(float* accs) {
  for (int i = threadIdx.x; i < ACC_FLOATS; i += 256) accs[i] = 0.0f;
}

extern "C" void kernel_launch(void* const* d_in, const int* in_sizes, int n_in,
                              void* d_out, int out_size, void* d_ws, size_t ws_size,
                              hipStream_t stream) {
  const float* recon = (const float*)d_in[0];
  const float* gt    = (const float*)d_in[1];
  const float* rnorm = (const float*)d_in[2];
  const float* gnorm = (const float*)d_in[3];
  const float* obj   = (const float*)d_in[4];
  const float* mean  = (const float*)d_in[5];
  const float* logv  = (const float*)d_in[6];
  const float* vw    = (const float*)d_in[7];
  float* out = (float*)d_out;

  // ws: accs grid (36KB) | keyR[4N] keyG[4N] priorK[4N] minHR[12H] minHG[12H]
  float* accs = (float*)d_ws;
  float* base = (float*)((char*)d_ws + ACC_FLOATS * sizeof(float));

  const size_t needed = ACC_FLOATS * sizeof(float)
                      + (3ull * JS4 * NKEY + 2ull * HC12 * NHT) * sizeof(float);

  if (ws_size >= needed) {
    float* keyR   = base;
    float* keyG   = keyR + (size_t)JS4 * NKEY;
    float* priorK = keyG + (size_t)JS4 * NKEY;
    float* minHR  = priorK + (size_t)JS4 * NKEY;
    float* minHG  = minHR + (size_t)HC12 * NHT;
    const int g1 = NB * OBJ_TILES * JS4 + NB * HC12;   // 384 + 384 = 768
    mega1t<<<g1, 256, 0, stream>>>(
        recon, gt, obj, keyR, keyG, priorK, minHR, minHG, accs);
    mega2s<<<M2_BLKS, 64, 0, stream>>>(
        recon, gt, rnorm, gnorm, obj, mean, logv, vw,
        keyR, keyG, priorK, minHR, minHG, accs);
    final_fb<<<1, 64, 0, stream>>>(accs, out);
  } else {
    init_small<<<1, 256, 0, stream>>>(accs);
    obj_mono<<<NB * 12, 256, 0, stream>>>(recon, gt, rnorm, gnorm, obj, accs);
    hand_full<<<NB * 4, 256, 0, stream>>>(recon, gt, obj, vw, accs);
    tail_nomins<<<(NB * NH + 255) / 256, 256, 0, stream>>>(recon, gt, mean, logv, accs);
    final_fb<<<1, 64, 0, stream>>>(accs, out);
  }
}